// Round 14
// baseline (1093.398 us; speedup 1.0000x reference)
//
#include <hip/hip_runtime.h>

#define DEVINL __device__ __forceinline__

constexpr int N_NODES  = 20000;
constexpr int N_EDGES  = 320000;
constexpr int IN_FEATS = 512;

static_assert(N_EDGES % 64 == 0, "edge tiling assumes E % 64 == 0");
static_assert(N_NODES % 16 == 0, "proj assumes N % 16 == 0");

typedef __attribute__((ext_vector_type(8))) short short8;  // 8 bf16 = 4 VGPR
typedef __attribute__((ext_vector_type(4))) float f32x4;   // MFMA acc

// ---- monotone float<->uint order encoding (for atomicMax-based segment_max) ----
DEVINL unsigned enc_f32(float v) {
  unsigned b = __float_as_uint(v);
  return (b & 0x80000000u) ? ~b : (b | 0x80000000u);
}
DEVINL float dec_f32(unsigned e) {
  unsigned b = (e & 0x80000000u) ? (e & 0x7FFFFFFFu) : ~e;
  return __uint_as_float(b);
}
// combine decode: empty segment (q==0) -> 0, else P + dec(Q)
DEVINL float dech(unsigned q, float p) { return q ? (p + dec_f32(q)) : 0.f; }

// ---- bf16 split helpers (A = hi + lo, each RNE bf16) ----
DEVINL unsigned short bf16_rne(float f) {
  unsigned u = __float_as_uint(f);
  u += 0x7FFFu + ((u >> 16) & 1u);
  return (unsigned short)(u >> 16);
}
DEVINL void split_bf16(float v, unsigned short& h, unsigned short& l) {
  h = bf16_rne(v);
  float hf = __uint_as_float((unsigned)h << 16);
  l = bf16_rne(v - hf);
}

// ---- async global->LDS (16B per lane, wave-uniform LDS base) ----
DEVINL void glds16(const unsigned short* g, unsigned short* l) {
  __builtin_amdgcn_global_load_lds(
      (const __attribute__((address_space(1))) unsigned int*)g,
      (__attribute__((address_space(3))) unsigned int*)l, 16, 0, 0);
}

// ---------------- CSR build (counting sort by dst) ----------------
__global__ void hist_kernel(const int* __restrict__ dst, int* __restrict__ cnt, int e) {
  int i = blockIdx.x * 256 + threadIdx.x;
  if (i < e) atomicAdd(&cnt[dst[i]], 1);
}
// scan phase 1 + dinv/dinv2 (folded; both read cnt)
__global__ void __launch_bounds__(256)
scan_p1(const int* __restrict__ cnt, int* __restrict__ rp, int* __restrict__ bsum,
        float* __restrict__ dinv, float* __restrict__ dinv2, int n) {
  __shared__ int buf[256];
  int i = blockIdx.x * 256 + threadIdx.x;
  int v = (i < n) ? cnt[i] : 0;
  if (i < n) {
    float s = rsqrtf((float)v + 1.0f);  // +1 self-loop
    dinv[i] = s;
    dinv2[i] = s * s;
  }
  buf[threadIdx.x] = v;
  __syncthreads();
  for (int off = 1; off < 256; off <<= 1) {
    int t = (threadIdx.x >= off) ? buf[threadIdx.x - off] : 0;
    __syncthreads();
    buf[threadIdx.x] += t;
    __syncthreads();
  }
  if (i < n) rp[i] = buf[threadIdx.x] - v;
  if (threadIdx.x == 255) bsum[blockIdx.x] = buf[255];
}
__global__ void __launch_bounds__(256)
scan_p2(int* __restrict__ bsum, int nb) {
  __shared__ int buf[256];
  int v = (threadIdx.x < nb) ? bsum[threadIdx.x] : 0;
  buf[threadIdx.x] = v;
  __syncthreads();
  for (int off = 1; off < 256; off <<= 1) {
    int t = (threadIdx.x >= off) ? buf[threadIdx.x - off] : 0;
    __syncthreads();
    buf[threadIdx.x] += t;
    __syncthreads();
  }
  if (threadIdx.x < nb) bsum[threadIdx.x] = buf[threadIdx.x] - v;  // exclusive
}
__global__ void __launch_bounds__(256)
scan_p3(int* __restrict__ rp, const int* __restrict__ bsum, int* __restrict__ cursor,
        int n, int e) {
  int i = blockIdx.x * 256 + threadIdx.x;
  if (i < n) {
    int v = rp[i] + bsum[blockIdx.x];
    rp[i] = v;
    cursor[i] = v;
  }
  if (i == 0) rp[n] = e;
}
__global__ void scatter_edges_kernel(const int* __restrict__ src, const int* __restrict__ dst,
                                     int* __restrict__ cursor, int* __restrict__ ssrc,
                                     int* __restrict__ sdst, int e) {
  int i = blockIdx.x * 256 + threadIdx.x;
  if (i < e) {
    int d = dst[i];
    int pos = atomicAdd(&cursor[d], 1);
    ssrc[pos] = src[i];
    sdst[pos] = d;
  }
}

// ---------------- merged setup: W frags + BN fold + W12/v1 + zero Q ----------------
DEVINL void bn1(const float* g, const float* b, const float* m, const float* v,
                float* sc, float* sh, int i) {
  float s = g[i] * rsqrtf(v[i] + 1e-5f);
  sc[i] = s;
  sh[i] = b[i] - m[i] * s;
}
DEVINL void wfrag1(const float* W, unsigned short* out, int e) {
  int k = e >> 7, c = e & 127;
  unsigned short h, l;
  split_bf16(W[e], h, l);
  int chunk = k >> 5, kq = (k >> 3) & 3, j = k & 7, ct = c >> 4, n = c & 15;
  int frag = (ct * 4 + kq) * 16 + n;
  size_t o = (size_t)chunk * 8192 + frag * 8 + j;
  out[o] = h;
  out[o + 4096] = l;
}
__global__ void setup_kernel(const float* __restrict__ e1W, const float* __restrict__ e2W,
                             const float* __restrict__ e3W, unsigned short* b1p,
                             unsigned short* b1q, unsigned short* b2p, unsigned short* b2q,
                             unsigned short* b3p, unsigned short* b3q,
                             const float* g1, const float* b1, const float* m1,
                             const float* v1bn, float* sc1, float* sh1, const float* g2,
                             const float* b2, const float* m2, const float* v2, float* sc2,
                             float* sh2, const float* g3, const float* b3, const float* m3,
                             const float* v3, float* sc3, float* sh3,
                             const float* __restrict__ Wg1, const float* __restrict__ Wg2,
                             const float* __restrict__ bg1, float* __restrict__ W12,
                             float* __restrict__ v1out, unsigned* __restrict__ Qzero) {
  int bid = blockIdx.x;
  if (bid < 512) {
    int g = bid * 256 + threadIdx.x;  // 131072 wfrag tasks
    if (g < 32768) wfrag1(e1W, b1p, g);
    else if (g < 65536) wfrag1(e1W + 32768, b1q, g - 32768);
    else if (g < 81920) wfrag1(e2W, b2p, g - 65536);
    else if (g < 98304) wfrag1(e2W + 16384, b2q, g - 81920);
    else if (g < 114688) wfrag1(e3W, b3p, g - 98304);
    else wfrag1(e3W + 16384, b3q, g - 114688);
  } else if (bid == 512) {
    for (int i = threadIdx.x; i < 1024; i += 256) {
      if (i < 512) bn1(g1, b1, m1, v1bn, sc1, sh1, i);
      else if (i < 768) bn1(g2, b2, m2, v2, sc2, sh2, i - 512);
      else bn1(g3, b3, m3, v3, sc3, sh3, i - 768);
    }
  } else if (bid < 545) {  // W12 = Wg1 @ Wg2  [64 x 128]
    int i = (bid - 513) * 256 + threadIdx.x;  // 8192 elems
    int r = i >> 7, c = i & 127;
    float acc = 0.f;
    for (int k = 0; k < 128; ++k) acc = fmaf(Wg1[r * 128 + k], Wg2[k * 128 + c], acc);
    W12[i] = acc;
  } else if (bid == 545) {  // v1 = bg1 @ Wg2  [128]
    if (threadIdx.x < 128) {
      int c = threadIdx.x;
      float acc = 0.f;
      for (int k = 0; k < 128; ++k) acc = fmaf(bg1[k], Wg2[k * 128 + c], acc);
      v1out[c] = acc;
    }
  } else {  // zero Q: 640000 uint4 over 2500 blocks
    int i = (bid - 546) * 256 + threadIdx.x;
    ((uint4*)Qzero)[i] = make_uint4(0u, 0u, 0u, 0u);
  }
}

// ---- mid: W123 = W12@Wg3, c1 = v1@Wg3, c2 = bg2@Wg3, + uvec1 (u1 = A~1) ----
__global__ void mid_kernel(const float* __restrict__ W12, const float* __restrict__ Wg3,
                           const float* __restrict__ v1, const float* __restrict__ bg2,
                           float* __restrict__ W123, float* __restrict__ c1,
                           float* __restrict__ c2, const int* __restrict__ row_ptr,
                           const int* __restrict__ ssrc, const float* __restrict__ dinv,
                           float* __restrict__ u1, float* __restrict__ w1, int n) {
  int bid = blockIdx.x;
  if (bid < 64) {  // W123 [64 x 256]
    int i = bid * 256 + threadIdx.x;
    int r = i >> 8, c = i & 255;
    float acc = 0.f;
    for (int k = 0; k < 128; ++k) acc = fmaf(W12[r * 128 + k], Wg3[k * 256 + c], acc);
    W123[i] = acc;
  } else if (bid == 64) {  // c1 [256]
    int c = threadIdx.x;
    float acc = 0.f;
    for (int k = 0; k < 128; ++k) acc = fmaf(v1[k], Wg3[k * 256 + c], acc);
    c1[c] = acc;
  } else if (bid == 65) {  // c2 [256]
    int c = threadIdx.x;
    float acc = 0.f;
    for (int k = 0; k < 128; ++k) acc = fmaf(bg2[k], Wg3[k * 256 + c], acc);
    c2[c] = acc;
  } else {  // uvec1
    int d = (bid - 66) * 256 + threadIdx.x;
    if (d >= n) return;
    float s = dinv[d];
    float acc = s;  // self term dinv_d
    int e = row_ptr[d], end = row_ptr[d + 1];
    for (; e < end; ++e) acc += dinv[ssrc[e]];
    float u = s * acc;
    u1[d] = u;
    w1[d] = s * u;  // pre-scaled for the next aggregate
  }
}
__global__ void uvec2_kernel(const int* __restrict__ row_ptr, const int* __restrict__ ssrc,
                             const float* __restrict__ dinv, const float* __restrict__ w1,
                             float* __restrict__ u2, int n) {
  int d = blockIdx.x * 256 + threadIdx.x;
  if (d >= n) return;
  float acc = w1[d];
  int e = row_ptr[d], end = row_ptr[d + 1];
  for (; e < end; ++e) acc += w1[ssrc[e]];
  u2[d] = dinv[d] * acc;
}

// combine: H = Q written ? P + dec(Q) : 0 ; re-zero Q for next layer
__global__ void combine_kernel(unsigned* __restrict__ Q, const float* __restrict__ P,
                               float* __restrict__ H, int n) {
  int i = blockIdx.x * 256 + threadIdx.x;
  if (i < n) {
    unsigned e = Q[i];
    H[i] = dech(e, P[i]);
    Q[i] = 0u;
  }
}

// ---------------- input projection: rows 0 mod 4 use Wm/bm, else Wc/bc ----------------
// writes Y0 = (x@W + b) * dinv[row]  (pre-scaled for the aggregate)
__global__ void __launch_bounds__(256)
proj_kernel(const float* __restrict__ X, const float* __restrict__ Wm,
            const float* __restrict__ bm, const float* __restrict__ Wc,
            const float* __restrict__ bc, const float* __restrict__ dinv,
            float* __restrict__ Y0) {
  __shared__ float xs[16][IN_FEATS];  // 32 KB
  int tid = threadIdx.x;
  int rowBase = blockIdx.x * 16;
  for (int i = 0; i < 8; ++i) {
    int idx = i * 256 + tid;
    int r = idx >> 7, kq = idx & 127;
    *reinterpret_cast<float4*>(&xs[r][kq * 4]) =
        *reinterpret_cast<const float4*>(X + (size_t)(rowBase + r) * IN_FEATS + kq * 4);
  }
  __syncthreads();
  int r4 = tid >> 6;  // residue class (wave-uniform); wave0 -> Wm, else Wc
  int j = tid & 63;
  const float* W = (r4 == 0) ? Wm : Wc;
  float a0 = 0.f, a1 = 0.f, a2 = 0.f, a3 = 0.f;
#pragma unroll 4
  for (int k = 0; k < IN_FEATS; ++k) {
    float w = W[k * 64 + j];
    a0 = fmaf(xs[r4][k], w, a0);
    a1 = fmaf(xs[r4 + 4][k], w, a1);
    a2 = fmaf(xs[r4 + 8][k], w, a2);
    a3 = fmaf(xs[r4 + 12][k], w, a3);
  }
  float b = (r4 == 0) ? bm[j] : bc[j];
  int r0 = rowBase + r4;
  Y0[(size_t)r0 * 64 + j] = (a0 + b) * dinv[r0];
  Y0[(size_t)(r0 + 4) * 64 + j] = (a1 + b) * dinv[r0 + 4];
  Y0[(size_t)(r0 + 8) * 64 + j] = (a2 + b) * dinv[r0 + 8];
  Y0[(size_t)(r0 + 12) * 64 + j] = (a3 + b) * dinv[r0 + 12];
}

// ------- GCN aggregate (CSR gather, float4): Z_d = mfac_d * (Y_d + sum Y_src) -------
template <int LOGF4>
__global__ void __launch_bounds__(256)
agg_kernel(const float* __restrict__ Y, const int* __restrict__ row_ptr,
           const int* __restrict__ ssrc, const float* __restrict__ mfac,
           float* __restrict__ Z, int n) {
  constexpr int F4 = 1 << LOGF4;
  int g = blockIdx.x * 256 + threadIdx.x;
  int d = g >> LOGF4, c4 = g & (F4 - 1);
  if (d >= n) return;
  const float4* Yp = (const float4*)Y;
  float4 a = Yp[(size_t)d * F4 + c4];  // self term
  float ax = a.x, ay = a.y, az = a.z, aw = a.w;
  int e = row_ptr[d], end = row_ptr[d + 1];
  for (; e + 7 < end; e += 8) {
    int s[8];
#pragma unroll
    for (int i = 0; i < 8; ++i) s[i] = ssrc[e + i];
    float4 v[8];
#pragma unroll
    for (int i = 0; i < 8; ++i) v[i] = Yp[(size_t)s[i] * F4 + c4];
#pragma unroll
    for (int i = 0; i < 8; ++i) {
      ax += v[i].x; ay += v[i].y; az += v[i].z; aw += v[i].w;
    }
  }
  for (; e < end; ++e) {
    float4 v = Yp[(size_t)ssrc[e] * F4 + c4];
    ax += v.x; ay += v.y; az += v.z; aw += v.w;
  }
  float s = mfac[d];
  ((float4*)Z)[(size_t)d * F4 + c4] = make_float4(ax * s, ay * s, az * s, aw * s);
}

// ------- collapsed GCN dense: G = Z3 @ W123 + u2 (x) c1 + u1 (x) c2 + b3 -------
__global__ void __launch_bounds__(256)
gemm_rank1_kernel(const float* __restrict__ X, const float* __restrict__ W,
                  const float* __restrict__ b3, const float* __restrict__ u1,
                  const float* __restrict__ u2, const float* __restrict__ c1,
                  const float* __restrict__ c2, float* __restrict__ H, int n) {
  constexpr int K = 64, F = 256;
  __shared__ float Xs[64][K + 1];
  __shared__ float Ws[K][65];
  int tid = threadIdx.x;
  int rowBase = blockIdx.x * 64;
  int colBase = blockIdx.y * 64;
  for (int idx = tid; idx < 64 * K; idx += 256) {
    int r = idx / K, k = idx % K;
    int row = rowBase + r;
    Xs[r][k] = (row < n) ? X[(size_t)row * K + k] : 0.f;
  }
  for (int idx = tid; idx < K * 64; idx += 256) {
    int k = idx >> 6, c = idx & 63;
    Ws[k][c] = W[(size_t)k * F + colBase + c];
  }
  __syncthreads();
  int tx = tid & 15, ty = tid >> 4;
  float acc[4][4] = {};
  for (int k = 0; k < K; ++k) {
    float a[4], b[4];
#pragma unroll
    for (int r = 0; r < 4; ++r) a[r] = Xs[ty * 4 + r][k];
#pragma unroll
    for (int c = 0; c < 4; ++c) b[c] = Ws[k][tx * 4 + c];
#pragma unroll
    for (int r = 0; r < 4; ++r)
#pragma unroll
      for (int c = 0; c < 4; ++c) acc[r][c] = fmaf(a[r], b[c], acc[r][c]);
  }
#pragma unroll
  for (int r = 0; r < 4; ++r) {
    int row = rowBase + ty * 4 + r;
    if (row < n) {
      float du2 = u2[row], du1 = u1[row];
#pragma unroll
      for (int c = 0; c < 4; ++c) {
        int col = colBase + tx * 4 + c;
        float v = acc[r][c] + du2 * c1[col] + du1 * c2[col] + b3[col];
        H[(size_t)row * F + col] = v;
      }
    }
  }
}

// ------- EdgeConv split-bf16 MFMA GEMM, v14 (1-chunk B staging, 8 blocks/CU) ----
// Round-7/11 causal datum: achieved gather BW scales with resident blocks.
// v13 was LDS-capped at 4 blocks/CU (35 KB).  Halving B staging to one 16 KB
// chunk -> ~18.7 KB/block -> 8 blocks/CU (CU max, 32 waves).  VGPR=60 in v13
// fits the 64-reg budget of __launch_bounds__(256,8) (spill sentinel:
// WRITE_SIZE).  2 barriers/chunk now, covered by 2x resident blocks.
DEVINL void proc8(const float4& va, const float4& vb, const float4& sa, const float4& sb,
                  const float4& ha, const float4& hb, short8& hi, short8& lo) {
  float f[8] = {va.x, va.y, va.z, va.w, vb.x, vb.y, vb.z, vb.w};
  float s[8] = {sa.x, sa.y, sa.z, sa.w, sb.x, sb.y, sb.z, sb.w};
  float t[8] = {ha.x, ha.y, ha.z, ha.w, hb.x, hb.y, hb.z, hb.w};
#pragma unroll
  for (int j = 0; j < 8; ++j) {
    float v = fmaxf(fmaf(f[j], s[j], t[j]), 0.f);
    unsigned short hh, ll;
    split_bf16(v, hh, ll);
    hi[j] = (short)hh;
    lo[j] = (short)ll;
  }
}

template <int C>
__global__ void __launch_bounds__(256, 8)
ec_mfma_kernel(const float* __restrict__ X, const int* __restrict__ ssrc,
               const int* __restrict__ sdst,
               const float* __restrict__ scaleQ, const float* __restrict__ shiftQ,
               const unsigned short* __restrict__ BfragQ,
               const float* __restrict__ scaleP, const float* __restrict__ shiftP,
               const unsigned short* __restrict__ BfragP,
               unsigned* __restrict__ outU, float* __restrict__ outP,
               int nrows, int edge_blocks) {
  constexpr int NCH = C / 32;
  __shared__ unsigned short Bmat[8192];   // 16 KB: 1 chunk (hi 8KB + lo 8KB)
  __shared__ float ss[2 * C];             // scale then shift
  __shared__ int de_s[64];
  const int tid = threadIdx.x, lane = tid & 63, wv = tid >> 6;
  const int q = lane >> 4, mn = lane & 15;
  const bool EDGE = (int)blockIdx.x < edge_blocks;
  const int base = (EDGE ? (int)blockIdx.x : (int)blockIdx.x - edge_blocks) * 64;
  const int koff = q * 8;
  const int lr = wv * 16 + mn;  // local row this lane loads A for

  const float* scale = EDGE ? scaleQ : scaleP;
  const float* shift = EDGE ? shiftQ : shiftP;
  const unsigned short* Bfrag = EDGE ? BfragQ : BfragP;

  int id, is = 0;
  if (EDGE) {
    if (tid < 64) de_s[tid] = sdst[base + tid];
    is = ssrc[base + lr];
    id = sdst[base + lr];
  } else {
    id = min(base + lr, nrows - 1);  // clamp; epilogue guards stores
  }
  const float* pd = X + (size_t)id * C + koff;
  const float* ps = EDGE ? X + (size_t)is * C + koff : nullptr;

  f32x4 acc[8];
#pragma unroll
  for (int i = 0; i < 8; ++i) acc[i] = (f32x4)0.f;

  // 2-slot A prefetch (all indices static after full unroll)
  float4 A[2][4];
#define LOAD_A(cc, slot)                              \
  {                                                   \
    const int kk_ = (cc) * 32;                        \
    A[slot][0] = *(const float4*)(pd + kk_);          \
    A[slot][1] = *(const float4*)(pd + kk_ + 4);      \
    if (EDGE) {                                       \
      A[slot][2] = *(const float4*)(ps + kk_);        \
      A[slot][3] = *(const float4*)(ps + kk_ + 4);    \
    }                                                 \
  }

  // prologue: A(0); scale/shift -> LDS; B chunk 0 -> LDS (DMA)
  LOAD_A(0, 0);
  {
    constexpr int NF4 = C / 4;
    if (tid < NF4)
      ((float4*)ss)[tid] = ((const float4*)scale)[tid];
    else if (tid < 2 * NF4)
      ((float4*)(ss + C))[tid - NF4] = ((const float4*)shift)[tid - NF4];
  }
  {
    const unsigned short* bs = Bfrag + lane * 8;
#pragma unroll
    for (int i = 0; i < 4; ++i) {
      int seg = wv * 4 + i;
      glds16(bs + seg * 512, Bmat + seg * 512);
    }
  }

#pragma unroll
  for (int c = 0; c < NCH; ++c) {
    if (c > 0) {
      __syncthreads();  // all waves done reading chunk c-1
      const unsigned short* bs = Bfrag + (size_t)c * 8192 + lane * 8;
#pragma unroll
      for (int i = 0; i < 4; ++i) {
        int seg = wv * 4 + i;
        glds16(bs + seg * 512, Bmat + seg * 512);
      }
    }
    __syncthreads();  // chunk DMA drained (c=0: also covers ss/de_s)
    const int kc = c * 32;
    if (c + 1 < NCH) LOAD_A(c + 1, (c + 1) & 1);  // issue before consuming slot c
    float4 sca = *(const float4*)&ss[kc + koff];
    float4 scb = *(const float4*)&ss[kc + koff + 4];
    float4 sha = *(const float4*)&ss[C + kc + koff];
    float4 shb = *(const float4*)&ss[C + kc + koff + 4];
    const int sl = c & 1;
    float4 u0, u1;
    if (EDGE) {
      u0 = make_float4(A[sl][2].x - A[sl][0].x, A[sl][2].y - A[sl][0].y,
                       A[sl][2].z - A[sl][0].z, A[sl][2].w - A[sl][0].w);
      u1 = make_float4(A[sl][3].x - A[sl][1].x, A[sl][3].y - A[sl][1].y,
                       A[sl][3].z - A[sl][1].z, A[sl][3].w - A[sl][1].w);
    } else {
      u0 = A[sl][0];
      u1 = A[sl][1];
    }
    short8 ah, al;
    proc8(u0, u1, sca, scb, sha, shb, ah, al);
#pragma unroll
    for (int ct = 0; ct < 8; ++ct) {
      int fi = ct * 64 + lane;
      short8 bh = *(const short8*)(Bmat + fi * 8);
      short8 bl = *(const short8*)(Bmat + 4096 + fi * 8);
      acc[ct] = __builtin_amdgcn_mfma_f32_16x16x32_bf16(ah, bh, acc[ct], 0, 0, 0);
      acc[ct] = __builtin_amdgcn_mfma_f32_16x16x32_bf16(ah, bl, acc[ct], 0, 0, 0);
      acc[ct] = __builtin_amdgcn_mfma_f32_16x16x32_bf16(al, bh, acc[ct], 0, 0, 0);
    }
  }
#undef LOAD_A

  // ---- epilogue: C/D layout col=lane&15, row=q*4+reg; rows dst-sorted -> run-merge ----
  if (EDGE) {
    int e0 = wv * 16 + q * 4;
#pragma unroll
    for (int ct = 0; ct < 8; ++ct) {
      int f = ct * 16 + mn;
      int prev = de_s[e0];
      float mv = acc[ct][0];
#pragma unroll
      for (int r = 1; r < 4; ++r) {
        int d = de_s[e0 + r];
        float v = acc[ct][r];
        if (d == prev) {
          mv = fmaxf(mv, v);
        } else {
          atomicMax(&outU[(size_t)prev * 128 + f], enc_f32(mv));
          prev = d;
          mv = v;
        }
      }
      atomicMax(&outU[(size_t)prev * 128 + f], enc_f32(mv));
    }
  } else {
    int r0 = base + wv * 16 + q * 4;
#pragma unroll
    for (int ct = 0; ct < 8; ++ct) {
      int f = ct * 16 + mn;
#pragma unroll
      for (int r = 0; r < 4; ++r) {
        int row = r0 + r;
        if (row < nrows) outP[(size_t)row * 128 + f] = acc[ct][r];
      }
    }
  }
}

// ------- final FC with fused combine: out = (P + max-decode(Q)) . Wfc + bfc -------
__global__ void __launch_bounds__(256)
fc_kernel(const unsigned* __restrict__ Q, const float* __restrict__ P,
          const float* __restrict__ Wfc, const float* __restrict__ bfc,
          float* __restrict__ out, int n) {
  int g = blockIdx.x * 256 + threadIdx.x;
  int node = g >> 6, lane = g & 63;
  if (node >= n) return;
  size_t b = (size_t)node * 128;
  float h0 = dech(Q[b + lane], P[b + lane]);
  float h1 = dech(Q[b + 64 + lane], P[b + 64 + lane]);
  float v = fmaf(h0, Wfc[lane], h1 * Wfc[64 + lane]);
#pragma unroll
  for (int off = 32; off > 0; off >>= 1) v += __shfl_down(v, off);
  if (lane == 0) out[node] = v + bfc[0];
}

extern "C" void kernel_launch(void* const* d_in, const int* in_sizes, int n_in,
                              void* d_out, int out_size, void* d_ws, size_t ws_size,
                              hipStream_t stream) {
  const float* x   = (const float*)d_in[0];
  const int*   ei  = (const int*)d_in[1];
  const float* Wm  = (const float*)d_in[2];
  const float* bm  = (const float*)d_in[3];
  const float* Wc  = (const float*)d_in[4];
  const float* bc  = (const float*)d_in[5];
  const float* Wg1 = (const float*)d_in[6];
  const float* bg1 = (const float*)d_in[7];
  const float* Wg2 = (const float*)d_in[8];
  const float* bg2 = (const float*)d_in[9];
  const float* Wg3 = (const float*)d_in[10];
  const float* bg3 = (const float*)d_in[11];
  const float* e1g = (const float*)d_in[12];
  const float* e1b = (const float*)d_in[13];
  const float* e1m = (const float*)d_in[14];
  const float* e1v = (const float*)d_in[15];
  const float* e1W = (const float*)d_in[16];
  const float* e2g = (const float*)d_in[17];
  const float* e2b = (const float*)d_in[18];
  const float* e2m = (const float*)d_in[19];
  const float* e2v = (const float*)d_in[20];
  const float* e2W = (const float*)d_in[21];
  const float* e3g = (const float*)d_in[22];
  const float* e3b = (const float*)d_in[23];
  const float* e3m = (const float*)d_in[24];
  const float* e3v = (const float*)d_in[25];
  const float* e3W = (const float*)d_in[26];
  const float* Wfc = (const float*)d_in[27];
  const float* bfc = (const float*)d_in[28];

  const int* src = ei;
  const int* dst = ei + N_EDGES;

  // ---- workspace layout (floats), ~63 MB ----
  float* ws    = (float*)d_ws;
  float* dinv  = ws;                                   // N
  float* dinv2 = dinv + N_NODES;                       // N
  float* u1    = dinv2 + N_NODES;                      // N
  float* w1    = u1 + N_NODES;                         // N
  float* u2    = w1 + N_NODES;                         // N
  float* y0    = u2 + N_NODES;                         // N*64
  float* za    = y0 + (size_t)N_NODES * 64;            // N*64
  float* zb    = za + (size_t)N_NODES * 64;            // N*64
  float* PQ    = zb + (size_t)N_NODES * 64;            // N*256 (P | Q)
  float* G     = PQ + (size_t)N_NODES * 256;           // N*256 (G; H1@base, H2@+N*128)
  float* sc1   = G + (size_t)N_NODES * 256;            // 512
  float* sh1   = sc1 + 512;
  float* sc2   = sh1 + 512;                            // 256
  float* sh2   = sc2 + 256;
  float* sc3   = sh2 + 256;
  float* sh3   = sc3 + 256;
  unsigned short* bf1p = (unsigned short*)(sh3 + 256);  // frag images, 512 KB total
  unsigned short* bf1q = bf1p + 65536;
  unsigned short* bf2p = bf1q + 65536;
  unsigned short* bf2q = bf2p + 32768;
  unsigned short* bf3p = bf2q + 32768;
  unsigned short* bf3q = bf3p + 32768;
  float* W12   = (float*)(bf3q + 32768);               // 64*128
  float* v1    = W12 + 8192;                           // 128
  float* W123  = v1 + 128;                             // 64*256
  float* c1    = W123 + 16384;                         // 256
  float* c2    = c1 + 256;                             // 256
  int* cnt     = (int*)(c2 + 256);                     // N
  int* row_ptr = cnt + N_NODES;                        // N+1
  int* cursor  = row_ptr + N_NODES + 1;                // N
  int* bsum    = cursor + N_NODES;                     // 256
  int* ssrc    = bsum + 256;                           // E
  int* sdst    = ssrc + N_EDGES;                       // E

  float*    Pbuf = PQ;
  unsigned* Qbuf = (unsigned*)(PQ + (size_t)N_NODES * 128);

  // ---- CSR build (counting sort by dst) + dinv/dinv2 ----
  hipMemsetAsync(cnt, 0, N_NODES * sizeof(int), stream);
  hist_kernel<<<N_EDGES / 256, 256, 0, stream>>>(dst, cnt, N_EDGES);
  scan_p1<<<79, 256, 0, stream>>>(cnt, row_ptr, bsum, dinv, dinv2, N_NODES);
  scan_p2<<<1, 256, 0, stream>>>(bsum, 79);
  scan_p3<<<79, 256, 0, stream>>>(row_ptr, bsum, cursor, N_NODES, N_EDGES);
  scatter_edges_kernel<<<N_EDGES / 256, 256, 0, stream>>>(src, dst, cursor, ssrc, sdst,
                                                          N_EDGES);

  // ---- setup: W frags + BN fold + W12/v1 + zero Q (one launch) ----
  setup_kernel<<<3046, 256, 0, stream>>>(e1W, e2W, e3W, bf1p, bf1q, bf2p, bf2q, bf3p, bf3q,
                                         e1g, e1b, e1m, e1v, sc1, sh1, e2g, e2b, e2m, e2v,
                                         sc2, sh2, e3g, e3b, e3m, e3v, sc3, sh3,
                                         Wg1, Wg2, bg1, W12, v1, Qbuf);

  // ---- mid: W123/c1/c2 + uvec1 ; then uvec2 ----
  mid_kernel<<<145, 256, 0, stream>>>(W12, Wg3, v1, bg2, W123, c1, c2, row_ptr, ssrc, dinv,
                                      u1, w1, N_NODES);
  uvec2_kernel<<<79, 256, 0, stream>>>(row_ptr, ssrc, dinv, w1, u2, N_NODES);

  // ---- linear GCN: G = A~^3 X0 W123 + u2 (x) c1 + u1 (x) c2 + b3 ----
  proj_kernel<<<N_NODES / 16, 256, 0, stream>>>(x, Wm, bm, Wc, bc, dinv, y0);
  agg_kernel<4><<<N_NODES * 16 / 256, 256, 0, stream>>>(y0, row_ptr, ssrc, dinv2, za, N_NODES);
  agg_kernel<4><<<N_NODES * 16 / 256, 256, 0, stream>>>(za, row_ptr, ssrc, dinv2, zb, N_NODES);
  agg_kernel<4><<<N_NODES * 16 / 256, 256, 0, stream>>>(zb, row_ptr, ssrc, dinv, za, N_NODES);
  dim3 grid4(313, 4);
  gemm_rank1_kernel<<<grid4, 256, 0, stream>>>(za, W123, bg3, u1, u2, c1, c2, G, N_NODES);

  const int EDGE_BLOCKS = N_EDGES / 64;             // 5000
  const int NODE_BLOCKS = (N_NODES + 63) / 64;      // 313
  const int EC_BLOCKS   = EDGE_BLOCKS + NODE_BLOCKS;
  const int NB_ELEM     = N_NODES * 128 / 256;      // 10000

  float* H1 = G;                        // combine1 -> G base (G dead after EC1)
  float* H2 = G + (size_t)N_NODES * 128;

  // EdgeConv 1: G [N,256] -> P/Q ; combine -> H1 [N,128]  (Q pre-zeroed by setup)
  ec_mfma_kernel<256><<<EC_BLOCKS, 256, 0, stream>>>(
      G, ssrc, sdst, sc1 + 256, sh1 + 256, bf1q, sc1, sh1, bf1p, Qbuf, Pbuf, N_NODES,
      EDGE_BLOCKS);
  combine_kernel<<<NB_ELEM, 256, 0, stream>>>(Qbuf, Pbuf, H1, N_NODES * 128);

  // EdgeConv 2: H1 -> P/Q ; combine -> H2
  ec_mfma_kernel<128><<<EC_BLOCKS, 256, 0, stream>>>(
      H1, ssrc, sdst, sc2 + 128, sh2 + 128, bf2q, sc2, sh2, bf2p, Qbuf, Pbuf, N_NODES,
      EDGE_BLOCKS);
  combine_kernel<<<NB_ELEM, 256, 0, stream>>>(Qbuf, Pbuf, H2, N_NODES * 128);

  // EdgeConv 3: H2 -> P/Q ; FC consumes P/Q directly (combine fused into FC)
  ec_mfma_kernel<128><<<EC_BLOCKS, 256, 0, stream>>>(
      H2, ssrc, sdst, sc3 + 128, sh3 + 128, bf3q, sc3, sh3, bf3p, Qbuf, Pbuf, N_NODES,
      EDGE_BLOCKS);
  fc_kernel<<<N_NODES * 64 / 256, 256, 0, stream>>>(Qbuf, Pbuf, Wfc, bfc, (float*)d_out,
                                                    N_NODES);
}

// Round 15
// 884.054 us; speedup vs baseline: 1.2368x; 1.2368x over previous
//
#include <hip/hip_runtime.h>

#define DEVINL __device__ __forceinline__

constexpr int N_NODES  = 20000;
constexpr int N_EDGES  = 320000;
constexpr int IN_FEATS = 512;

static_assert(N_EDGES % 64 == 0, "edge tiling assumes E % 64 == 0");
static_assert(N_NODES % 16 == 0, "proj assumes N % 16 == 0");

typedef __attribute__((ext_vector_type(8))) short short8;  // 8 bf16 = 4 VGPR
typedef __attribute__((ext_vector_type(4))) float f32x4;   // MFMA acc

// ---- monotone float<->uint order encoding (for atomicMax-based segment_max) ----
DEVINL unsigned enc_f32(float v) {
  unsigned b = __float_as_uint(v);
  return (b & 0x80000000u) ? ~b : (b | 0x80000000u);
}
DEVINL float dec_f32(unsigned e) {
  unsigned b = (e & 0x80000000u) ? (e & 0x7FFFFFFFu) : ~e;
  return __uint_as_float(b);
}
// combine decode: empty segment (q==0) -> 0, else P + dec(Q)
DEVINL float dech(unsigned q, float p) { return q ? (p + dec_f32(q)) : 0.f; }

// ---- bf16 split helpers (A = hi + lo, each RNE bf16) ----
DEVINL unsigned short bf16_rne(float f) {
  unsigned u = __float_as_uint(f);
  u += 0x7FFFu + ((u >> 16) & 1u);
  return (unsigned short)(u >> 16);
}
DEVINL void split_bf16(float v, unsigned short& h, unsigned short& l) {
  h = bf16_rne(v);
  float hf = __uint_as_float((unsigned)h << 16);
  l = bf16_rne(v - hf);
}

// ---- async global->LDS (16B per lane, wave-uniform LDS base) ----
DEVINL void glds16(const unsigned short* g, unsigned short* l) {
  __builtin_amdgcn_global_load_lds(
      (const __attribute__((address_space(1))) unsigned int*)g,
      (__attribute__((address_space(3))) unsigned int*)l, 16, 0, 0);
}

// ---------------- CSR build (counting sort by dst) ----------------
__global__ void hist_kernel(const int* __restrict__ dst, int* __restrict__ cnt, int e) {
  int i = blockIdx.x * 256 + threadIdx.x;
  if (i < e) atomicAdd(&cnt[dst[i]], 1);
}
// scan phase 1 + dinv/dinv2 (folded; both read cnt)
__global__ void __launch_bounds__(256)
scan_p1(const int* __restrict__ cnt, int* __restrict__ rp, int* __restrict__ bsum,
        float* __restrict__ dinv, float* __restrict__ dinv2, int n) {
  __shared__ int buf[256];
  int i = blockIdx.x * 256 + threadIdx.x;
  int v = (i < n) ? cnt[i] : 0;
  if (i < n) {
    float s = rsqrtf((float)v + 1.0f);  // +1 self-loop
    dinv[i] = s;
    dinv2[i] = s * s;
  }
  buf[threadIdx.x] = v;
  __syncthreads();
  for (int off = 1; off < 256; off <<= 1) {
    int t = (threadIdx.x >= off) ? buf[threadIdx.x - off] : 0;
    __syncthreads();
    buf[threadIdx.x] += t;
    __syncthreads();
  }
  if (i < n) rp[i] = buf[threadIdx.x] - v;
  if (threadIdx.x == 255) bsum[blockIdx.x] = buf[255];
}
__global__ void __launch_bounds__(256)
scan_p2(int* __restrict__ bsum, int nb) {
  __shared__ int buf[256];
  int v = (threadIdx.x < nb) ? bsum[threadIdx.x] : 0;
  buf[threadIdx.x] = v;
  __syncthreads();
  for (int off = 1; off < 256; off <<= 1) {
    int t = (threadIdx.x >= off) ? buf[threadIdx.x - off] : 0;
    __syncthreads();
    buf[threadIdx.x] += t;
    __syncthreads();
  }
  if (threadIdx.x < nb) bsum[threadIdx.x] = buf[threadIdx.x] - v;  // exclusive
}
__global__ void __launch_bounds__(256)
scan_p3(int* __restrict__ rp, const int* __restrict__ bsum, int* __restrict__ cursor,
        int n, int e) {
  int i = blockIdx.x * 256 + threadIdx.x;
  if (i < n) {
    int v = rp[i] + bsum[blockIdx.x];
    rp[i] = v;
    cursor[i] = v;
  }
  if (i == 0) rp[n] = e;
}
__global__ void scatter_edges_kernel(const int* __restrict__ src, const int* __restrict__ dst,
                                     int* __restrict__ cursor, int* __restrict__ ssrc,
                                     int* __restrict__ sdst, int e) {
  int i = blockIdx.x * 256 + threadIdx.x;
  if (i < e) {
    int d = dst[i];
    int pos = atomicAdd(&cursor[d], 1);
    ssrc[pos] = src[i];
    sdst[pos] = d;
  }
}

// ---------------- merged setup: W frags + BN fold + W12/v1 + zero Q ----------------
DEVINL void bn1(const float* g, const float* b, const float* m, const float* v,
                float* sc, float* sh, int i) {
  float s = g[i] * rsqrtf(v[i] + 1e-5f);
  sc[i] = s;
  sh[i] = b[i] - m[i] * s;
}
DEVINL void wfrag1(const float* W, unsigned short* out, int e) {
  int k = e >> 7, c = e & 127;
  unsigned short h, l;
  split_bf16(W[e], h, l);
  int chunk = k >> 5, kq = (k >> 3) & 3, j = k & 7, ct = c >> 4, n = c & 15;
  int frag = (ct * 4 + kq) * 16 + n;
  size_t o = (size_t)chunk * 8192 + frag * 8 + j;
  out[o] = h;
  out[o + 4096] = l;
}
__global__ void setup_kernel(const float* __restrict__ e1W, const float* __restrict__ e2W,
                             const float* __restrict__ e3W, unsigned short* b1p,
                             unsigned short* b1q, unsigned short* b2p, unsigned short* b2q,
                             unsigned short* b3p, unsigned short* b3q,
                             const float* g1, const float* b1, const float* m1,
                             const float* v1bn, float* sc1, float* sh1, const float* g2,
                             const float* b2, const float* m2, const float* v2, float* sc2,
                             float* sh2, const float* g3, const float* b3, const float* m3,
                             const float* v3, float* sc3, float* sh3,
                             const float* __restrict__ Wg1, const float* __restrict__ Wg2,
                             const float* __restrict__ bg1, float* __restrict__ W12,
                             float* __restrict__ v1out, unsigned* __restrict__ Qzero) {
  int bid = blockIdx.x;
  if (bid < 512) {
    int g = bid * 256 + threadIdx.x;  // 131072 wfrag tasks
    if (g < 32768) wfrag1(e1W, b1p, g);
    else if (g < 65536) wfrag1(e1W + 32768, b1q, g - 32768);
    else if (g < 81920) wfrag1(e2W, b2p, g - 65536);
    else if (g < 98304) wfrag1(e2W + 16384, b2q, g - 81920);
    else if (g < 114688) wfrag1(e3W, b3p, g - 98304);
    else wfrag1(e3W + 16384, b3q, g - 114688);
  } else if (bid == 512) {
    for (int i = threadIdx.x; i < 1024; i += 256) {
      if (i < 512) bn1(g1, b1, m1, v1bn, sc1, sh1, i);
      else if (i < 768) bn1(g2, b2, m2, v2, sc2, sh2, i - 512);
      else bn1(g3, b3, m3, v3, sc3, sh3, i - 768);
    }
  } else if (bid < 545) {  // W12 = Wg1 @ Wg2  [64 x 128]
    int i = (bid - 513) * 256 + threadIdx.x;  // 8192 elems
    int r = i >> 7, c = i & 127;
    float acc = 0.f;
    for (int k = 0; k < 128; ++k) acc = fmaf(Wg1[r * 128 + k], Wg2[k * 128 + c], acc);
    W12[i] = acc;
  } else if (bid == 545) {  // v1 = bg1 @ Wg2  [128]
    if (threadIdx.x < 128) {
      int c = threadIdx.x;
      float acc = 0.f;
      for (int k = 0; k < 128; ++k) acc = fmaf(bg1[k], Wg2[k * 128 + c], acc);
      v1out[c] = acc;
    }
  } else {  // zero Q: 640000 uint4 over 2500 blocks
    int i = (bid - 546) * 256 + threadIdx.x;
    ((uint4*)Qzero)[i] = make_uint4(0u, 0u, 0u, 0u);
  }
}

// ---- mid: W123 = W12@Wg3, c1 = v1@Wg3, c2 = bg2@Wg3, + uvec1 (u1 = A~1) ----
__global__ void mid_kernel(const float* __restrict__ W12, const float* __restrict__ Wg3,
                           const float* __restrict__ v1, const float* __restrict__ bg2,
                           float* __restrict__ W123, float* __restrict__ c1,
                           float* __restrict__ c2, const int* __restrict__ row_ptr,
                           const int* __restrict__ ssrc, const float* __restrict__ dinv,
                           float* __restrict__ u1, float* __restrict__ w1, int n) {
  int bid = blockIdx.x;
  if (bid < 64) {  // W123 [64 x 256]
    int i = bid * 256 + threadIdx.x;
    int r = i >> 8, c = i & 255;
    float acc = 0.f;
    for (int k = 0; k < 128; ++k) acc = fmaf(W12[r * 128 + k], Wg3[k * 256 + c], acc);
    W123[i] = acc;
  } else if (bid == 64) {  // c1 [256]
    int c = threadIdx.x;
    float acc = 0.f;
    for (int k = 0; k < 128; ++k) acc = fmaf(v1[k], Wg3[k * 256 + c], acc);
    c1[c] = acc;
  } else if (bid == 65) {  // c2 [256]
    int c = threadIdx.x;
    float acc = 0.f;
    for (int k = 0; k < 128; ++k) acc = fmaf(bg2[k], Wg3[k * 256 + c], acc);
    c2[c] = acc;
  } else {  // uvec1
    int d = (bid - 66) * 256 + threadIdx.x;
    if (d >= n) return;
    float s = dinv[d];
    float acc = s;  // self term dinv_d
    int e = row_ptr[d], end = row_ptr[d + 1];
    for (; e < end; ++e) acc += dinv[ssrc[e]];
    float u = s * acc;
    u1[d] = u;
    w1[d] = s * u;  // pre-scaled for the next aggregate
  }
}
__global__ void uvec2_kernel(const int* __restrict__ row_ptr, const int* __restrict__ ssrc,
                             const float* __restrict__ dinv, const float* __restrict__ w1,
                             float* __restrict__ u2, int n) {
  int d = blockIdx.x * 256 + threadIdx.x;
  if (d >= n) return;
  float acc = w1[d];
  int e = row_ptr[d], end = row_ptr[d + 1];
  for (; e < end; ++e) acc += w1[ssrc[e]];
  u2[d] = dinv[d] * acc;
}

// combine: H = Q written ? P + dec(Q) : 0 ; re-zero Q for next layer
__global__ void combine_kernel(unsigned* __restrict__ Q, const float* __restrict__ P,
                               float* __restrict__ H, int n) {
  int i = blockIdx.x * 256 + threadIdx.x;
  if (i < n) {
    unsigned e = Q[i];
    H[i] = dech(e, P[i]);
    Q[i] = 0u;
  }
}

// ---------------- input projection: rows 0 mod 4 use Wm/bm, else Wc/bc ----------------
// writes Y0 = (x@W + b) * dinv[row]  (pre-scaled for the aggregate)
__global__ void __launch_bounds__(256)
proj_kernel(const float* __restrict__ X, const float* __restrict__ Wm,
            const float* __restrict__ bm, const float* __restrict__ Wc,
            const float* __restrict__ bc, const float* __restrict__ dinv,
            float* __restrict__ Y0) {
  __shared__ float xs[16][IN_FEATS];  // 32 KB
  int tid = threadIdx.x;
  int rowBase = blockIdx.x * 16;
  for (int i = 0; i < 8; ++i) {
    int idx = i * 256 + tid;
    int r = idx >> 7, kq = idx & 127;
    *reinterpret_cast<float4*>(&xs[r][kq * 4]) =
        *reinterpret_cast<const float4*>(X + (size_t)(rowBase + r) * IN_FEATS + kq * 4);
  }
  __syncthreads();
  int r4 = tid >> 6;  // residue class (wave-uniform); wave0 -> Wm, else Wc
  int j = tid & 63;
  const float* W = (r4 == 0) ? Wm : Wc;
  float a0 = 0.f, a1 = 0.f, a2 = 0.f, a3 = 0.f;
#pragma unroll 4
  for (int k = 0; k < IN_FEATS; ++k) {
    float w = W[k * 64 + j];
    a0 = fmaf(xs[r4][k], w, a0);
    a1 = fmaf(xs[r4 + 4][k], w, a1);
    a2 = fmaf(xs[r4 + 8][k], w, a2);
    a3 = fmaf(xs[r4 + 12][k], w, a3);
  }
  float b = (r4 == 0) ? bm[j] : bc[j];
  int r0 = rowBase + r4;
  Y0[(size_t)r0 * 64 + j] = (a0 + b) * dinv[r0];
  Y0[(size_t)(r0 + 4) * 64 + j] = (a1 + b) * dinv[r0 + 4];
  Y0[(size_t)(r0 + 8) * 64 + j] = (a2 + b) * dinv[r0 + 8];
  Y0[(size_t)(r0 + 12) * 64 + j] = (a3 + b) * dinv[r0 + 12];
}

// ------- GCN aggregate (CSR gather, float4): Z_d = mfac_d * (Y_d + sum Y_src) -------
template <int LOGF4>
__global__ void __launch_bounds__(256)
agg_kernel(const float* __restrict__ Y, const int* __restrict__ row_ptr,
           const int* __restrict__ ssrc, const float* __restrict__ mfac,
           float* __restrict__ Z, int n) {
  constexpr int F4 = 1 << LOGF4;
  int g = blockIdx.x * 256 + threadIdx.x;
  int d = g >> LOGF4, c4 = g & (F4 - 1);
  if (d >= n) return;
  const float4* Yp = (const float4*)Y;
  float4 a = Yp[(size_t)d * F4 + c4];  // self term
  float ax = a.x, ay = a.y, az = a.z, aw = a.w;
  int e = row_ptr[d], end = row_ptr[d + 1];
  for (; e + 7 < end; e += 8) {
    int s[8];
#pragma unroll
    for (int i = 0; i < 8; ++i) s[i] = ssrc[e + i];
    float4 v[8];
#pragma unroll
    for (int i = 0; i < 8; ++i) v[i] = Yp[(size_t)s[i] * F4 + c4];
#pragma unroll
    for (int i = 0; i < 8; ++i) {
      ax += v[i].x; ay += v[i].y; az += v[i].z; aw += v[i].w;
    }
  }
  for (; e < end; ++e) {
    float4 v = Yp[(size_t)ssrc[e] * F4 + c4];
    ax += v.x; ay += v.y; az += v.z; aw += v.w;
  }
  float s = mfac[d];
  ((float4*)Z)[(size_t)d * F4 + c4] = make_float4(ax * s, ay * s, az * s, aw * s);
}

// ------- collapsed GCN dense: G = Z3 @ W123 + u2 (x) c1 + u1 (x) c2 + b3 -------
__global__ void __launch_bounds__(256)
gemm_rank1_kernel(const float* __restrict__ X, const float* __restrict__ W,
                  const float* __restrict__ b3, const float* __restrict__ u1,
                  const float* __restrict__ u2, const float* __restrict__ c1,
                  const float* __restrict__ c2, float* __restrict__ H, int n) {
  constexpr int K = 64, F = 256;
  __shared__ float Xs[64][K + 1];
  __shared__ float Ws[K][65];
  int tid = threadIdx.x;
  int rowBase = blockIdx.x * 64;
  int colBase = blockIdx.y * 64;
  for (int idx = tid; idx < 64 * K; idx += 256) {
    int r = idx / K, k = idx % K;
    int row = rowBase + r;
    Xs[r][k] = (row < n) ? X[(size_t)row * K + k] : 0.f;
  }
  for (int idx = tid; idx < K * 64; idx += 256) {
    int k = idx >> 6, c = idx & 63;
    Ws[k][c] = W[(size_t)k * F + colBase + c];
  }
  __syncthreads();
  int tx = tid & 15, ty = tid >> 4;
  float acc[4][4] = {};
  for (int k = 0; k < K; ++k) {
    float a[4], b[4];
#pragma unroll
    for (int r = 0; r < 4; ++r) a[r] = Xs[ty * 4 + r][k];
#pragma unroll
    for (int c = 0; c < 4; ++c) b[c] = Ws[k][tx * 4 + c];
#pragma unroll
    for (int r = 0; r < 4; ++r)
#pragma unroll
      for (int c = 0; c < 4; ++c) acc[r][c] = fmaf(a[r], b[c], acc[r][c]);
  }
#pragma unroll
  for (int r = 0; r < 4; ++r) {
    int row = rowBase + ty * 4 + r;
    if (row < n) {
      float du2 = u2[row], du1 = u1[row];
#pragma unroll
      for (int c = 0; c < 4; ++c) {
        int col = colBase + tx * 4 + c;
        float v = acc[r][c] + du2 * c1[col] + du1 * c2[col] + b3[col];
        H[(size_t)row * F + col] = v;
      }
    }
  }
}

// ------- EdgeConv split-bf16 MFMA GEMM, v15 (1-chunk B staging, 6 blocks/CU) ----
// Round-14 lesson: (256,8)'s 64-VGPR budget cannot hold the 32-VGPR acc ->
// compiler clamped to 32 VGPR and spilled (WRITE 80MB->1.1GB).  (256,6) gives
// an 84-VGPR budget >= the 60 this kernel measures, with 24 waves/CU (1.5x
// v13's 16) and 18.9 KB LDS (1-chunk staging) fitting 6 blocks by LDS.
DEVINL void proc8(const float4& va, const float4& vb, const float4& sa, const float4& sb,
                  const float4& ha, const float4& hb, short8& hi, short8& lo) {
  float f[8] = {va.x, va.y, va.z, va.w, vb.x, vb.y, vb.z, vb.w};
  float s[8] = {sa.x, sa.y, sa.z, sa.w, sb.x, sb.y, sb.z, sb.w};
  float t[8] = {ha.x, ha.y, ha.z, ha.w, hb.x, hb.y, hb.z, hb.w};
#pragma unroll
  for (int j = 0; j < 8; ++j) {
    float v = fmaxf(fmaf(f[j], s[j], t[j]), 0.f);
    unsigned short hh, ll;
    split_bf16(v, hh, ll);
    hi[j] = (short)hh;
    lo[j] = (short)ll;
  }
}

template <int C>
__global__ void __launch_bounds__(256, 6)
ec_mfma_kernel(const float* __restrict__ X, const int* __restrict__ ssrc,
               const int* __restrict__ sdst,
               const float* __restrict__ scaleQ, const float* __restrict__ shiftQ,
               const unsigned short* __restrict__ BfragQ,
               const float* __restrict__ scaleP, const float* __restrict__ shiftP,
               const unsigned short* __restrict__ BfragP,
               unsigned* __restrict__ outU, float* __restrict__ outP,
               int nrows, int edge_blocks) {
  constexpr int NCH = C / 32;
  __shared__ unsigned short Bmat[8192];   // 16 KB: 1 chunk (hi 8KB + lo 8KB)
  __shared__ float ss[2 * C];             // scale then shift
  __shared__ int de_s[64];
  const int tid = threadIdx.x, lane = tid & 63, wv = tid >> 6;
  const int q = lane >> 4, mn = lane & 15;
  const bool EDGE = (int)blockIdx.x < edge_blocks;
  const int base = (EDGE ? (int)blockIdx.x : (int)blockIdx.x - edge_blocks) * 64;
  const int koff = q * 8;
  const int lr = wv * 16 + mn;  // local row this lane loads A for

  const float* scale = EDGE ? scaleQ : scaleP;
  const float* shift = EDGE ? shiftQ : shiftP;
  const unsigned short* Bfrag = EDGE ? BfragQ : BfragP;

  int id, is = 0;
  if (EDGE) {
    if (tid < 64) de_s[tid] = sdst[base + tid];
    is = ssrc[base + lr];
    id = sdst[base + lr];
  } else {
    id = min(base + lr, nrows - 1);  // clamp; epilogue guards stores
  }
  const float* pd = X + (size_t)id * C + koff;
  const float* ps = EDGE ? X + (size_t)is * C + koff : nullptr;

  f32x4 acc[8];
#pragma unroll
  for (int i = 0; i < 8; ++i) acc[i] = (f32x4)0.f;

  // 2-slot A prefetch (all indices static after full unroll)
  float4 A[2][4];
#define LOAD_A(cc, slot)                              \
  {                                                   \
    const int kk_ = (cc) * 32;                        \
    A[slot][0] = *(const float4*)(pd + kk_);          \
    A[slot][1] = *(const float4*)(pd + kk_ + 4);      \
    if (EDGE) {                                       \
      A[slot][2] = *(const float4*)(ps + kk_);        \
      A[slot][3] = *(const float4*)(ps + kk_ + 4);    \
    }                                                 \
  }

  // prologue: A(0); scale/shift -> LDS; B chunk 0 -> LDS (DMA)
  LOAD_A(0, 0);
  {
    constexpr int NF4 = C / 4;
    if (tid < NF4)
      ((float4*)ss)[tid] = ((const float4*)scale)[tid];
    else if (tid < 2 * NF4)
      ((float4*)(ss + C))[tid - NF4] = ((const float4*)shift)[tid - NF4];
  }
  {
    const unsigned short* bs = Bfrag + lane * 8;
#pragma unroll
    for (int i = 0; i < 4; ++i) {
      int seg = wv * 4 + i;
      glds16(bs + seg * 512, Bmat + seg * 512);
    }
  }

#pragma unroll
  for (int c = 0; c < NCH; ++c) {
    if (c > 0) {
      __syncthreads();  // all waves done reading chunk c-1
      const unsigned short* bs = Bfrag + (size_t)c * 8192 + lane * 8;
#pragma unroll
      for (int i = 0; i < 4; ++i) {
        int seg = wv * 4 + i;
        glds16(bs + seg * 512, Bmat + seg * 512);
      }
    }
    __syncthreads();  // chunk DMA drained (c=0: also covers ss/de_s)
    const int kc = c * 32;
    if (c + 1 < NCH) LOAD_A(c + 1, (c + 1) & 1);  // issue before consuming slot c
    float4 sca = *(const float4*)&ss[kc + koff];
    float4 scb = *(const float4*)&ss[kc + koff + 4];
    float4 sha = *(const float4*)&ss[C + kc + koff];
    float4 shb = *(const float4*)&ss[C + kc + koff + 4];
    const int sl = c & 1;
    float4 u0, u1;
    if (EDGE) {
      u0 = make_float4(A[sl][2].x - A[sl][0].x, A[sl][2].y - A[sl][0].y,
                       A[sl][2].z - A[sl][0].z, A[sl][2].w - A[sl][0].w);
      u1 = make_float4(A[sl][3].x - A[sl][1].x, A[sl][3].y - A[sl][1].y,
                       A[sl][3].z - A[sl][1].z, A[sl][3].w - A[sl][1].w);
    } else {
      u0 = A[sl][0];
      u1 = A[sl][1];
    }
    short8 ah, al;
    proc8(u0, u1, sca, scb, sha, shb, ah, al);
#pragma unroll
    for (int ct = 0; ct < 8; ++ct) {
      int fi = ct * 64 + lane;
      short8 bh = *(const short8*)(Bmat + fi * 8);
      short8 bl = *(const short8*)(Bmat + 4096 + fi * 8);
      acc[ct] = __builtin_amdgcn_mfma_f32_16x16x32_bf16(ah, bh, acc[ct], 0, 0, 0);
      acc[ct] = __builtin_amdgcn_mfma_f32_16x16x32_bf16(ah, bl, acc[ct], 0, 0, 0);
      acc[ct] = __builtin_amdgcn_mfma_f32_16x16x32_bf16(al, bh, acc[ct], 0, 0, 0);
    }
  }
#undef LOAD_A

  // ---- epilogue: C/D layout col=lane&15, row=q*4+reg; rows dst-sorted -> run-merge ----
  if (EDGE) {
    int e0 = wv * 16 + q * 4;
#pragma unroll
    for (int ct = 0; ct < 8; ++ct) {
      int f = ct * 16 + mn;
      int prev = de_s[e0];
      float mv = acc[ct][0];
#pragma unroll
      for (int r = 1; r < 4; ++r) {
        int d = de_s[e0 + r];
        float v = acc[ct][r];
        if (d == prev) {
          mv = fmaxf(mv, v);
        } else {
          atomicMax(&outU[(size_t)prev * 128 + f], enc_f32(mv));
          prev = d;
          mv = v;
        }
      }
      atomicMax(&outU[(size_t)prev * 128 + f], enc_f32(mv));
    }
  } else {
    int r0 = base + wv * 16 + q * 4;
#pragma unroll
    for (int ct = 0; ct < 8; ++ct) {
      int f = ct * 16 + mn;
#pragma unroll
      for (int r = 0; r < 4; ++r) {
        int row = r0 + r;
        if (row < nrows) outP[(size_t)row * 128 + f] = acc[ct][r];
      }
    }
  }
}

// ------- final FC with fused combine: out = (P + max-decode(Q)) . Wfc + bfc -------
__global__ void __launch_bounds__(256)
fc_kernel(const unsigned* __restrict__ Q, const float* __restrict__ P,
          const float* __restrict__ Wfc, const float* __restrict__ bfc,
          float* __restrict__ out, int n) {
  int g = blockIdx.x * 256 + threadIdx.x;
  int node = g >> 6, lane = g & 63;
  if (node >= n) return;
  size_t b = (size_t)node * 128;
  float h0 = dech(Q[b + lane], P[b + lane]);
  float h1 = dech(Q[b + 64 + lane], P[b + 64 + lane]);
  float v = fmaf(h0, Wfc[lane], h1 * Wfc[64 + lane]);
#pragma unroll
  for (int off = 32; off > 0; off >>= 1) v += __shfl_down(v, off);
  if (lane == 0) out[node] = v + bfc[0];
}

extern "C" void kernel_launch(void* const* d_in, const int* in_sizes, int n_in,
                              void* d_out, int out_size, void* d_ws, size_t ws_size,
                              hipStream_t stream) {
  const float* x   = (const float*)d_in[0];
  const int*   ei  = (const int*)d_in[1];
  const float* Wm  = (const float*)d_in[2];
  const float* bm  = (const float*)d_in[3];
  const float* Wc  = (const float*)d_in[4];
  const float* bc  = (const float*)d_in[5];
  const float* Wg1 = (const float*)d_in[6];
  const float* bg1 = (const float*)d_in[7];
  const float* Wg2 = (const float*)d_in[8];
  const float* bg2 = (const float*)d_in[9];
  const float* Wg3 = (const float*)d_in[10];
  const float* bg3 = (const float*)d_in[11];
  const float* e1g = (const float*)d_in[12];
  const float* e1b = (const float*)d_in[13];
  const float* e1m = (const float*)d_in[14];
  const float* e1v = (const float*)d_in[15];
  const float* e1W = (const float*)d_in[16];
  const float* e2g = (const float*)d_in[17];
  const float* e2b = (const float*)d_in[18];
  const float* e2m = (const float*)d_in[19];
  const float* e2v = (const float*)d_in[20];
  const float* e2W = (const float*)d_in[21];
  const float* e3g = (const float*)d_in[22];
  const float* e3b = (const float*)d_in[23];
  const float* e3m = (const float*)d_in[24];
  const float* e3v = (const float*)d_in[25];
  const float* e3W = (const float*)d_in[26];
  const float* Wfc = (const float*)d_in[27];
  const float* bfc = (const float*)d_in[28];

  const int* src = ei;
  const int* dst = ei + N_EDGES;

  // ---- workspace layout (floats), ~63 MB ----
  float* ws    = (float*)d_ws;
  float* dinv  = ws;                                   // N
  float* dinv2 = dinv + N_NODES;                       // N
  float* u1    = dinv2 + N_NODES;                      // N
  float* w1    = u1 + N_NODES;                         // N
  float* u2    = w1 + N_NODES;                         // N
  float* y0    = u2 + N_NODES;                         // N*64
  float* za    = y0 + (size_t)N_NODES * 64;            // N*64
  float* zb    = za + (size_t)N_NODES * 64;            // N*64
  float* PQ    = zb + (size_t)N_NODES * 64;            // N*256 (P | Q)
  float* G     = PQ + (size_t)N_NODES * 256;           // N*256 (G; H1@base, H2@+N*128)
  float* sc1   = G + (size_t)N_NODES * 256;            // 512
  float* sh1   = sc1 + 512;
  float* sc2   = sh1 + 512;                            // 256
  float* sh2   = sc2 + 256;
  float* sc3   = sh2 + 256;
  float* sh3   = sc3 + 256;
  unsigned short* bf1p = (unsigned short*)(sh3 + 256);  // frag images, 512 KB total
  unsigned short* bf1q = bf1p + 65536;
  unsigned short* bf2p = bf1q + 65536;
  unsigned short* bf2q = bf2p + 32768;
  unsigned short* bf3p = bf2q + 32768;
  unsigned short* bf3q = bf3p + 32768;
  float* W12   = (float*)(bf3q + 32768);               // 64*128
  float* v1    = W12 + 8192;                           // 128
  float* W123  = v1 + 128;                             // 64*256
  float* c1    = W123 + 16384;                         // 256
  float* c2    = c1 + 256;                             // 256
  int* cnt     = (int*)(c2 + 256);                     // N
  int* row_ptr = cnt + N_NODES;                        // N+1
  int* cursor  = row_ptr + N_NODES + 1;                // N
  int* bsum    = cursor + N_NODES;                     // 256
  int* ssrc    = bsum + 256;                           // E
  int* sdst    = ssrc + N_EDGES;                       // E

  float*    Pbuf = PQ;
  unsigned* Qbuf = (unsigned*)(PQ + (size_t)N_NODES * 128);

  // ---- CSR build (counting sort by dst) + dinv/dinv2 ----
  hipMemsetAsync(cnt, 0, N_NODES * sizeof(int), stream);
  hist_kernel<<<N_EDGES / 256, 256, 0, stream>>>(dst, cnt, N_EDGES);
  scan_p1<<<79, 256, 0, stream>>>(cnt, row_ptr, bsum, dinv, dinv2, N_NODES);
  scan_p2<<<1, 256, 0, stream>>>(bsum, 79);
  scan_p3<<<79, 256, 0, stream>>>(row_ptr, bsum, cursor, N_NODES, N_EDGES);
  scatter_edges_kernel<<<N_EDGES / 256, 256, 0, stream>>>(src, dst, cursor, ssrc, sdst,
                                                          N_EDGES);

  // ---- setup: W frags + BN fold + W12/v1 + zero Q (one launch) ----
  setup_kernel<<<3046, 256, 0, stream>>>(e1W, e2W, e3W, bf1p, bf1q, bf2p, bf2q, bf3p, bf3q,
                                         e1g, e1b, e1m, e1v, sc1, sh1, e2g, e2b, e2m, e2v,
                                         sc2, sh2, e3g, e3b, e3m, e3v, sc3, sh3,
                                         Wg1, Wg2, bg1, W12, v1, Qbuf);

  // ---- mid: W123/c1/c2 + uvec1 ; then uvec2 ----
  mid_kernel<<<145, 256, 0, stream>>>(W12, Wg3, v1, bg2, W123, c1, c2, row_ptr, ssrc, dinv,
                                      u1, w1, N_NODES);
  uvec2_kernel<<<79, 256, 0, stream>>>(row_ptr, ssrc, dinv, w1, u2, N_NODES);

  // ---- linear GCN: G = A~^3 X0 W123 + u2 (x) c1 + u1 (x) c2 + b3 ----
  proj_kernel<<<N_NODES / 16, 256, 0, stream>>>(x, Wm, bm, Wc, bc, dinv, y0);
  agg_kernel<4><<<N_NODES * 16 / 256, 256, 0, stream>>>(y0, row_ptr, ssrc, dinv2, za, N_NODES);
  agg_kernel<4><<<N_NODES * 16 / 256, 256, 0, stream>>>(za, row_ptr, ssrc, dinv2, zb, N_NODES);
  agg_kernel<4><<<N_NODES * 16 / 256, 256, 0, stream>>>(zb, row_ptr, ssrc, dinv, za, N_NODES);
  dim3 grid4(313, 4);
  gemm_rank1_kernel<<<grid4, 256, 0, stream>>>(za, W123, bg3, u1, u2, c1, c2, G, N_NODES);

  const int EDGE_BLOCKS = N_EDGES / 64;             // 5000
  const int NODE_BLOCKS = (N_NODES + 63) / 64;      // 313
  const int EC_BLOCKS   = EDGE_BLOCKS + NODE_BLOCKS;
  const int NB_ELEM     = N_NODES * 128 / 256;      // 10000

  float* H1 = G;                        // combine1 -> G base (G dead after EC1)
  float* H2 = G + (size_t)N_NODES * 128;

  // EdgeConv 1: G [N,256] -> P/Q ; combine -> H1 [N,128]  (Q pre-zeroed by setup)
  ec_mfma_kernel<256><<<EC_BLOCKS, 256, 0, stream>>>(
      G, ssrc, sdst, sc1 + 256, sh1 + 256, bf1q, sc1, sh1, bf1p, Qbuf, Pbuf, N_NODES,
      EDGE_BLOCKS);
  combine_kernel<<<NB_ELEM, 256, 0, stream>>>(Qbuf, Pbuf, H1, N_NODES * 128);

  // EdgeConv 2: H1 -> P/Q ; combine -> H2
  ec_mfma_kernel<128><<<EC_BLOCKS, 256, 0, stream>>>(
      H1, ssrc, sdst, sc2 + 128, sh2 + 128, bf2q, sc2, sh2, bf2p, Qbuf, Pbuf, N_NODES,
      EDGE_BLOCKS);
  combine_kernel<<<NB_ELEM, 256, 0, stream>>>(Qbuf, Pbuf, H2, N_NODES * 128);

  // EdgeConv 3: H2 -> P/Q ; FC consumes P/Q directly (combine fused into FC)
  ec_mfma_kernel<128><<<EC_BLOCKS, 256, 0, stream>>>(
      H2, ssrc, sdst, sc3 + 128, sh3 + 128, bf3q, sc3, sh3, bf3p, Qbuf, Pbuf, N_NODES,
      EDGE_BLOCKS);
  fc_kernel<<<N_NODES * 64 / 256, 256, 0, stream>>>(Qbuf, Pbuf, Wfc, bfc, (float*)d_out,
                                                    N_NODES);
}

// Round 16
// 647.122 us; speedup vs baseline: 1.6896x; 1.3661x over previous
//
#include <hip/hip_runtime.h>

#define DEVINL __device__ __forceinline__

constexpr int N_NODES  = 20000;
constexpr int N_EDGES  = 320000;
constexpr int IN_FEATS = 512;

static_assert(N_EDGES % 64 == 0, "edge tiling assumes E % 64 == 0");
static_assert(N_NODES % 16 == 0, "proj assumes N % 16 == 0");

typedef __attribute__((ext_vector_type(8))) short short8;  // 8 bf16 = 4 VGPR
typedef __attribute__((ext_vector_type(4))) float f32x4;   // MFMA acc

// ---- monotone float<->uint order encoding (for atomicMax-based segment_max) ----
DEVINL unsigned enc_f32(float v) {
  unsigned b = __float_as_uint(v);
  return (b & 0x80000000u) ? ~b : (b | 0x80000000u);
}
DEVINL float dec_f32(unsigned e) {
  unsigned b = (e & 0x80000000u) ? (e & 0x7FFFFFFFu) : ~e;
  return __uint_as_float(b);
}
// combine decode: empty segment (q==0) -> 0, else P + dec(Q)
DEVINL float dech(unsigned q, float p) { return q ? (p + dec_f32(q)) : 0.f; }

// ---- bf16 split helpers (A = hi + lo, each RNE bf16) ----
DEVINL unsigned short bf16_rne(float f) {
  unsigned u = __float_as_uint(f);
  u += 0x7FFFu + ((u >> 16) & 1u);
  return (unsigned short)(u >> 16);
}
DEVINL void split_bf16(float v, unsigned short& h, unsigned short& l) {
  h = bf16_rne(v);
  float hf = __uint_as_float((unsigned)h << 16);
  l = bf16_rne(v - hf);
}

// ---- async global->LDS (16B per lane, wave-uniform LDS base) ----
DEVINL void glds16(const unsigned short* g, unsigned short* l) {
  __builtin_amdgcn_global_load_lds(
      (const __attribute__((address_space(1))) unsigned int*)g,
      (__attribute__((address_space(3))) unsigned int*)l, 16, 0, 0);
}

// ---------------- CSR build (counting sort by dst) ----------------
__global__ void hist_kernel(const int* __restrict__ dst, int* __restrict__ cnt, int e) {
  int i = blockIdx.x * 256 + threadIdx.x;
  if (i < e) atomicAdd(&cnt[dst[i]], 1);
}
// scan phase 1 + dinv/dinv2 (folded; both read cnt)
__global__ void __launch_bounds__(256)
scan_p1(const int* __restrict__ cnt, int* __restrict__ rp, int* __restrict__ bsum,
        float* __restrict__ dinv, float* __restrict__ dinv2, int n) {
  __shared__ int buf[256];
  int i = blockIdx.x * 256 + threadIdx.x;
  int v = (i < n) ? cnt[i] : 0;
  if (i < n) {
    float s = rsqrtf((float)v + 1.0f);  // +1 self-loop
    dinv[i] = s;
    dinv2[i] = s * s;
  }
  buf[threadIdx.x] = v;
  __syncthreads();
  for (int off = 1; off < 256; off <<= 1) {
    int t = (threadIdx.x >= off) ? buf[threadIdx.x - off] : 0;
    __syncthreads();
    buf[threadIdx.x] += t;
    __syncthreads();
  }
  if (i < n) rp[i] = buf[threadIdx.x] - v;
  if (threadIdx.x == 255) bsum[blockIdx.x] = buf[255];
}
__global__ void __launch_bounds__(256)
scan_p2(int* __restrict__ bsum, int nb) {
  __shared__ int buf[256];
  int v = (threadIdx.x < nb) ? bsum[threadIdx.x] : 0;
  buf[threadIdx.x] = v;
  __syncthreads();
  for (int off = 1; off < 256; off <<= 1) {
    int t = (threadIdx.x >= off) ? buf[threadIdx.x - off] : 0;
    __syncthreads();
    buf[threadIdx.x] += t;
    __syncthreads();
  }
  if (threadIdx.x < nb) bsum[threadIdx.x] = buf[threadIdx.x] - v;  // exclusive
}
__global__ void __launch_bounds__(256)
scan_p3(int* __restrict__ rp, const int* __restrict__ bsum, int* __restrict__ cursor,
        int n, int e) {
  int i = blockIdx.x * 256 + threadIdx.x;
  if (i < n) {
    int v = rp[i] + bsum[blockIdx.x];
    rp[i] = v;
    cursor[i] = v;
  }
  if (i == 0) rp[n] = e;
}
__global__ void scatter_edges_kernel(const int* __restrict__ src, const int* __restrict__ dst,
                                     int* __restrict__ cursor, int* __restrict__ ssrc,
                                     int* __restrict__ sdst, int e) {
  int i = blockIdx.x * 256 + threadIdx.x;
  if (i < e) {
    int d = dst[i];
    int pos = atomicAdd(&cursor[d], 1);
    ssrc[pos] = src[i];
    sdst[pos] = d;
  }
}

// ---------------- merged setup: W frags + BN fold + W12/v1 + zero Q ----------------
DEVINL void bn1(const float* g, const float* b, const float* m, const float* v,
                float* sc, float* sh, int i) {
  float s = g[i] * rsqrtf(v[i] + 1e-5f);
  sc[i] = s;
  sh[i] = b[i] - m[i] * s;
}
DEVINL void wfrag1(const float* W, unsigned short* out, int e) {
  int k = e >> 7, c = e & 127;
  unsigned short h, l;
  split_bf16(W[e], h, l);
  int chunk = k >> 5, kq = (k >> 3) & 3, j = k & 7, ct = c >> 4, n = c & 15;
  int frag = (ct * 4 + kq) * 16 + n;
  size_t o = (size_t)chunk * 8192 + frag * 8 + j;
  out[o] = h;
  out[o + 4096] = l;
}
__global__ void setup_kernel(const float* __restrict__ e1W, const float* __restrict__ e2W,
                             const float* __restrict__ e3W, unsigned short* b1p,
                             unsigned short* b1q, unsigned short* b2p, unsigned short* b2q,
                             unsigned short* b3p, unsigned short* b3q,
                             const float* g1, const float* b1, const float* m1,
                             const float* v1bn, float* sc1, float* sh1, const float* g2,
                             const float* b2, const float* m2, const float* v2, float* sc2,
                             float* sh2, const float* g3, const float* b3, const float* m3,
                             const float* v3, float* sc3, float* sh3,
                             const float* __restrict__ Wg1, const float* __restrict__ Wg2,
                             const float* __restrict__ bg1, float* __restrict__ W12,
                             float* __restrict__ v1out, unsigned* __restrict__ Qzero) {
  int bid = blockIdx.x;
  if (bid < 512) {
    int g = bid * 256 + threadIdx.x;  // 131072 wfrag tasks
    if (g < 32768) wfrag1(e1W, b1p, g);
    else if (g < 65536) wfrag1(e1W + 32768, b1q, g - 32768);
    else if (g < 81920) wfrag1(e2W, b2p, g - 65536);
    else if (g < 98304) wfrag1(e2W + 16384, b2q, g - 81920);
    else if (g < 114688) wfrag1(e3W, b3p, g - 98304);
    else wfrag1(e3W + 16384, b3q, g - 114688);
  } else if (bid == 512) {
    for (int i = threadIdx.x; i < 1024; i += 256) {
      if (i < 512) bn1(g1, b1, m1, v1bn, sc1, sh1, i);
      else if (i < 768) bn1(g2, b2, m2, v2, sc2, sh2, i - 512);
      else bn1(g3, b3, m3, v3, sc3, sh3, i - 768);
    }
  } else if (bid < 545) {  // W12 = Wg1 @ Wg2  [64 x 128]
    int i = (bid - 513) * 256 + threadIdx.x;  // 8192 elems
    int r = i >> 7, c = i & 127;
    float acc = 0.f;
    for (int k = 0; k < 128; ++k) acc = fmaf(Wg1[r * 128 + k], Wg2[k * 128 + c], acc);
    W12[i] = acc;
  } else if (bid == 545) {  // v1 = bg1 @ Wg2  [128]
    if (threadIdx.x < 128) {
      int c = threadIdx.x;
      float acc = 0.f;
      for (int k = 0; k < 128; ++k) acc = fmaf(bg1[k], Wg2[k * 128 + c], acc);
      v1out[c] = acc;
    }
  } else {  // zero Q: 640000 uint4 over 2500 blocks
    int i = (bid - 546) * 256 + threadIdx.x;
    ((uint4*)Qzero)[i] = make_uint4(0u, 0u, 0u, 0u);
  }
}

// ---- mid: W123 = W12@Wg3, c1 = v1@Wg3, c2 = bg2@Wg3, + uvec1 (u1 = A~1) ----
__global__ void mid_kernel(const float* __restrict__ W12, const float* __restrict__ Wg3,
                           const float* __restrict__ v1, const float* __restrict__ bg2,
                           float* __restrict__ W123, float* __restrict__ c1,
                           float* __restrict__ c2, const int* __restrict__ row_ptr,
                           const int* __restrict__ ssrc, const float* __restrict__ dinv,
                           float* __restrict__ u1, float* __restrict__ w1, int n) {
  int bid = blockIdx.x;
  if (bid < 64) {  // W123 [64 x 256]
    int i = bid * 256 + threadIdx.x;
    int r = i >> 8, c = i & 255;
    float acc = 0.f;
    for (int k = 0; k < 128; ++k) acc = fmaf(W12[r * 128 + k], Wg3[k * 256 + c], acc);
    W123[i] = acc;
  } else if (bid == 64) {  // c1 [256]
    int c = threadIdx.x;
    float acc = 0.f;
    for (int k = 0; k < 128; ++k) acc = fmaf(v1[k], Wg3[k * 256 + c], acc);
    c1[c] = acc;
  } else if (bid == 65) {  // c2 [256]
    int c = threadIdx.x;
    float acc = 0.f;
    for (int k = 0; k < 128; ++k) acc = fmaf(bg2[k], Wg3[k * 256 + c], acc);
    c2[c] = acc;
  } else {  // uvec1
    int d = (bid - 66) * 256 + threadIdx.x;
    if (d >= n) return;
    float s = dinv[d];
    float acc = s;  // self term dinv_d
    int e = row_ptr[d], end = row_ptr[d + 1];
    for (; e < end; ++e) acc += dinv[ssrc[e]];
    float u = s * acc;
    u1[d] = u;
    w1[d] = s * u;  // pre-scaled for the next aggregate
  }
}
__global__ void uvec2_kernel(const int* __restrict__ row_ptr, const int* __restrict__ ssrc,
                             const float* __restrict__ dinv, const float* __restrict__ w1,
                             float* __restrict__ u2, int n) {
  int d = blockIdx.x * 256 + threadIdx.x;
  if (d >= n) return;
  float acc = w1[d];
  int e = row_ptr[d], end = row_ptr[d + 1];
  for (; e < end; ++e) acc += w1[ssrc[e]];
  u2[d] = dinv[d] * acc;
}

// combine: H = Q written ? P + dec(Q) : 0 ; re-zero Q for next layer
__global__ void combine_kernel(unsigned* __restrict__ Q, const float* __restrict__ P,
                               float* __restrict__ H, int n) {
  int i = blockIdx.x * 256 + threadIdx.x;
  if (i < n) {
    unsigned e = Q[i];
    H[i] = dech(e, P[i]);
    Q[i] = 0u;
  }
}

// ---------------- input projection: rows 0 mod 4 use Wm/bm, else Wc/bc ----------------
// writes Y0 = (x@W + b) * dinv[row]  (pre-scaled for the aggregate)
__global__ void __launch_bounds__(256)
proj_kernel(const float* __restrict__ X, const float* __restrict__ Wm,
            const float* __restrict__ bm, const float* __restrict__ Wc,
            const float* __restrict__ bc, const float* __restrict__ dinv,
            float* __restrict__ Y0) {
  __shared__ float xs[16][IN_FEATS];  // 32 KB
  int tid = threadIdx.x;
  int rowBase = blockIdx.x * 16;
  for (int i = 0; i < 8; ++i) {
    int idx = i * 256 + tid;
    int r = idx >> 7, kq = idx & 127;
    *reinterpret_cast<float4*>(&xs[r][kq * 4]) =
        *reinterpret_cast<const float4*>(X + (size_t)(rowBase + r) * IN_FEATS + kq * 4);
  }
  __syncthreads();
  int r4 = tid >> 6;  // residue class (wave-uniform); wave0 -> Wm, else Wc
  int j = tid & 63;
  const float* W = (r4 == 0) ? Wm : Wc;
  float a0 = 0.f, a1 = 0.f, a2 = 0.f, a3 = 0.f;
#pragma unroll 4
  for (int k = 0; k < IN_FEATS; ++k) {
    float w = W[k * 64 + j];
    a0 = fmaf(xs[r4][k], w, a0);
    a1 = fmaf(xs[r4 + 4][k], w, a1);
    a2 = fmaf(xs[r4 + 8][k], w, a2);
    a3 = fmaf(xs[r4 + 12][k], w, a3);
  }
  float b = (r4 == 0) ? bm[j] : bc[j];
  int r0 = rowBase + r4;
  Y0[(size_t)r0 * 64 + j] = (a0 + b) * dinv[r0];
  Y0[(size_t)(r0 + 4) * 64 + j] = (a1 + b) * dinv[r0 + 4];
  Y0[(size_t)(r0 + 8) * 64 + j] = (a2 + b) * dinv[r0 + 8];
  Y0[(size_t)(r0 + 12) * 64 + j] = (a3 + b) * dinv[r0 + 12];
}

// ------- GCN aggregate (CSR gather, float4): Z_d = mfac_d * (Y_d + sum Y_src) -------
template <int LOGF4>
__global__ void __launch_bounds__(256)
agg_kernel(const float* __restrict__ Y, const int* __restrict__ row_ptr,
           const int* __restrict__ ssrc, const float* __restrict__ mfac,
           float* __restrict__ Z, int n) {
  constexpr int F4 = 1 << LOGF4;
  int g = blockIdx.x * 256 + threadIdx.x;
  int d = g >> LOGF4, c4 = g & (F4 - 1);
  if (d >= n) return;
  const float4* Yp = (const float4*)Y;
  float4 a = Yp[(size_t)d * F4 + c4];  // self term
  float ax = a.x, ay = a.y, az = a.z, aw = a.w;
  int e = row_ptr[d], end = row_ptr[d + 1];
  for (; e + 7 < end; e += 8) {
    int s[8];
#pragma unroll
    for (int i = 0; i < 8; ++i) s[i] = ssrc[e + i];
    float4 v[8];
#pragma unroll
    for (int i = 0; i < 8; ++i) v[i] = Yp[(size_t)s[i] * F4 + c4];
#pragma unroll
    for (int i = 0; i < 8; ++i) {
      ax += v[i].x; ay += v[i].y; az += v[i].z; aw += v[i].w;
    }
  }
  for (; e < end; ++e) {
    float4 v = Yp[(size_t)ssrc[e] * F4 + c4];
    ax += v.x; ay += v.y; az += v.z; aw += v.w;
  }
  float s = mfac[d];
  ((float4*)Z)[(size_t)d * F4 + c4] = make_float4(ax * s, ay * s, az * s, aw * s);
}

// ------- collapsed GCN dense: G = Z3 @ W123 + u2 (x) c1 + u1 (x) c2 + b3 -------
__global__ void __launch_bounds__(256)
gemm_rank1_kernel(const float* __restrict__ X, const float* __restrict__ W,
                  const float* __restrict__ b3, const float* __restrict__ u1,
                  const float* __restrict__ u2, const float* __restrict__ c1,
                  const float* __restrict__ c2, float* __restrict__ H, int n) {
  constexpr int K = 64, F = 256;
  __shared__ float Xs[64][K + 1];
  __shared__ float Ws[K][65];
  int tid = threadIdx.x;
  int rowBase = blockIdx.x * 64;
  int colBase = blockIdx.y * 64;
  for (int idx = tid; idx < 64 * K; idx += 256) {
    int r = idx / K, k = idx % K;
    int row = rowBase + r;
    Xs[r][k] = (row < n) ? X[(size_t)row * K + k] : 0.f;
  }
  for (int idx = tid; idx < K * 64; idx += 256) {
    int k = idx >> 6, c = idx & 63;
    Ws[k][c] = W[(size_t)k * F + colBase + c];
  }
  __syncthreads();
  int tx = tid & 15, ty = tid >> 4;
  float acc[4][4] = {};
  for (int k = 0; k < K; ++k) {
    float a[4], b[4];
#pragma unroll
    for (int r = 0; r < 4; ++r) a[r] = Xs[ty * 4 + r][k];
#pragma unroll
    for (int c = 0; c < 4; ++c) b[c] = Ws[k][tx * 4 + c];
#pragma unroll
    for (int r = 0; r < 4; ++r)
#pragma unroll
      for (int c = 0; c < 4; ++c) acc[r][c] = fmaf(a[r], b[c], acc[r][c]);
  }
#pragma unroll
  for (int r = 0; r < 4; ++r) {
    int row = rowBase + ty * 4 + r;
    if (row < n) {
      float du2 = u2[row], du1 = u1[row];
#pragma unroll
      for (int c = 0; c < 4; ++c) {
        int col = colBase + tx * 4 + c;
        float v = acc[r][c] + du2 * c1[col] + du1 * c2[col] + b3[col];
        H[(size_t)row * F + col] = v;
      }
    }
  }
}

// ------- EdgeConv split-bf16 MFMA GEMM, v16 (= v13 exactly: 2-chunk staging, 4/CU) ----
// r14/r15 lesson (final): HW VGPR bins are coarse; any launch_bounds above 4
// waves/SIMD allocates <64 VGPR and spills the ~60-reg live set (WRITE_SIZE
// 80MB -> 0.7-1.1GB).  (256,4) with 32KB LDS is the only spill-free point.
DEVINL void proc8(const float4& va, const float4& vb, const float4& sa, const float4& sb,
                  const float4& ha, const float4& hb, short8& hi, short8& lo) {
  float f[8] = {va.x, va.y, va.z, va.w, vb.x, vb.y, vb.z, vb.w};
  float s[8] = {sa.x, sa.y, sa.z, sa.w, sb.x, sb.y, sb.z, sb.w};
  float t[8] = {ha.x, ha.y, ha.z, ha.w, hb.x, hb.y, hb.z, hb.w};
#pragma unroll
  for (int j = 0; j < 8; ++j) {
    float v = fmaxf(fmaf(f[j], s[j], t[j]), 0.f);
    unsigned short hh, ll;
    split_bf16(v, hh, ll);
    hi[j] = (short)hh;
    lo[j] = (short)ll;
  }
}

template <int C>
__global__ void __launch_bounds__(256, 4)
ec_mfma_kernel(const float* __restrict__ X, const int* __restrict__ ssrc,
               const int* __restrict__ sdst,
               const float* __restrict__ scaleQ, const float* __restrict__ shiftQ,
               const unsigned short* __restrict__ BfragQ,
               const float* __restrict__ scaleP, const float* __restrict__ shiftP,
               const unsigned short* __restrict__ BfragP,
               unsigned* __restrict__ outU, float* __restrict__ outP,
               int nrows, int edge_blocks) {
  constexpr int NCH = C / 32;
  constexpr int NSTAGE = NCH / 2;
  __shared__ unsigned short Bmat[16384];  // 32 KB: 2 chunks x (hi 8KB + lo 8KB)
  __shared__ float ss[2 * C];             // scale then shift
  __shared__ int de_s[64];
  const int tid = threadIdx.x, lane = tid & 63, wv = tid >> 6;
  const int q = lane >> 4, mn = lane & 15;
  const bool EDGE = (int)blockIdx.x < edge_blocks;
  const int base = (EDGE ? (int)blockIdx.x : (int)blockIdx.x - edge_blocks) * 64;
  const int koff = q * 8;
  const int lr = wv * 16 + mn;  // local row this lane loads A for

  const float* scale = EDGE ? scaleQ : scaleP;
  const float* shift = EDGE ? shiftQ : shiftP;
  const unsigned short* Bfrag = EDGE ? BfragQ : BfragP;

  int id, is = 0;
  if (EDGE) {
    if (tid < 64) de_s[tid] = sdst[base + tid];
    is = ssrc[base + lr];
    id = sdst[base + lr];
  } else {
    id = min(base + lr, nrows - 1);  // clamp; epilogue guards stores
  }
  const float* pd = X + (size_t)id * C + koff;
  const float* ps = EDGE ? X + (size_t)is * C + koff : nullptr;

  f32x4 acc[8];
#pragma unroll
  for (int i = 0; i < 8; ++i) acc[i] = (f32x4)0.f;

  // 2-slot A prefetch (all indices static after full unroll)
  float4 A[2][4];
#define LOAD_A(cc, slot)                              \
  {                                                   \
    const int kk_ = (cc) * 32;                        \
    A[slot][0] = *(const float4*)(pd + kk_);          \
    A[slot][1] = *(const float4*)(pd + kk_ + 4);      \
    if (EDGE) {                                       \
      A[slot][2] = *(const float4*)(ps + kk_);        \
      A[slot][3] = *(const float4*)(ps + kk_ + 4);    \
    }                                                 \
  }

  // prologue: A(0); scale/shift -> LDS; B stage 0 -> LDS (DMA)
  LOAD_A(0, 0);
  {
    constexpr int NF4 = C / 4;
    if (tid < NF4)
      ((float4*)ss)[tid] = ((const float4*)scale)[tid];
    else if (tid < 2 * NF4)
      ((float4*)(ss + C))[tid - NF4] = ((const float4*)shift)[tid - NF4];
  }
  {
    const unsigned short* bs = Bfrag + lane * 8;
#pragma unroll
    for (int i = 0; i < 8; ++i) {
      int seg = wv * 8 + i;
      glds16(bs + seg * 512, Bmat + seg * 512);
    }
  }

#pragma unroll
  for (int s = 0; s < NSTAGE; ++s) {
    if (s > 0) {
      __syncthreads();  // all waves done reading previous stage of Bmat
      const unsigned short* bs = Bfrag + (size_t)s * 16384 + lane * 8;
#pragma unroll
      for (int i = 0; i < 8; ++i) {
        int seg = wv * 8 + i;
        glds16(bs + seg * 512, Bmat + seg * 512);
      }
    }
    __syncthreads();  // stage DMA drained (also covers ss/de_s on s=0)
#pragma unroll
    for (int cc = 0; cc < 2; ++cc) {
      const int c = s * 2 + cc;
      const int kc = c * 32;
      if (c + 1 < NCH) LOAD_A(c + 1, (c + 1) & 1);  // issue before consuming slot c
      float4 sca = *(const float4*)&ss[kc + koff];
      float4 scb = *(const float4*)&ss[kc + koff + 4];
      float4 sha = *(const float4*)&ss[C + kc + koff];
      float4 shb = *(const float4*)&ss[C + kc + koff + 4];
      const int sl = c & 1;
      float4 u0, u1;
      if (EDGE) {
        u0 = make_float4(A[sl][2].x - A[sl][0].x, A[sl][2].y - A[sl][0].y,
                         A[sl][2].z - A[sl][0].z, A[sl][2].w - A[sl][0].w);
        u1 = make_float4(A[sl][3].x - A[sl][1].x, A[sl][3].y - A[sl][1].y,
                         A[sl][3].z - A[sl][1].z, A[sl][3].w - A[sl][1].w);
      } else {
        u0 = A[sl][0];
        u1 = A[sl][1];
      }
      short8 ah, al;
      proc8(u0, u1, sca, scb, sha, shb, ah, al);
      const unsigned short* Bc = Bmat + cc * 8192;
#pragma unroll
      for (int ct = 0; ct < 8; ++ct) {
        int fi = ct * 64 + lane;
        short8 bh = *(const short8*)(Bc + fi * 8);
        short8 bl = *(const short8*)(Bc + 4096 + fi * 8);
        acc[ct] = __builtin_amdgcn_mfma_f32_16x16x32_bf16(ah, bh, acc[ct], 0, 0, 0);
        acc[ct] = __builtin_amdgcn_mfma_f32_16x16x32_bf16(ah, bl, acc[ct], 0, 0, 0);
        acc[ct] = __builtin_amdgcn_mfma_f32_16x16x32_bf16(al, bh, acc[ct], 0, 0, 0);
      }
    }
  }
#undef LOAD_A

  // ---- epilogue: C/D layout col=lane&15, row=q*4+reg; rows dst-sorted -> run-merge ----
  if (EDGE) {
    int e0 = wv * 16 + q * 4;
#pragma unroll
    for (int ct = 0; ct < 8; ++ct) {
      int f = ct * 16 + mn;
      int prev = de_s[e0];
      float mv = acc[ct][0];
#pragma unroll
      for (int r = 1; r < 4; ++r) {
        int d = de_s[e0 + r];
        float v = acc[ct][r];
        if (d == prev) {
          mv = fmaxf(mv, v);
        } else {
          atomicMax(&outU[(size_t)prev * 128 + f], enc_f32(mv));
          prev = d;
          mv = v;
        }
      }
      atomicMax(&outU[(size_t)prev * 128 + f], enc_f32(mv));
    }
  } else {
    int r0 = base + wv * 16 + q * 4;
#pragma unroll
    for (int ct = 0; ct < 8; ++ct) {
      int f = ct * 16 + mn;
#pragma unroll
      for (int r = 0; r < 4; ++r) {
        int row = r0 + r;
        if (row < nrows) outP[(size_t)row * 128 + f] = acc[ct][r];
      }
    }
  }
}

// ------- final FC with fused combine: out = (P + max-decode(Q)) . Wfc + bfc -------
__global__ void __launch_bounds__(256)
fc_kernel(const unsigned* __restrict__ Q, const float* __restrict__ P,
          const float* __restrict__ Wfc, const float* __restrict__ bfc,
          float* __restrict__ out, int n) {
  int g = blockIdx.x * 256 + threadIdx.x;
  int node = g >> 6, lane = g & 63;
  if (node >= n) return;
  size_t b = (size_t)node * 128;
  float h0 = dech(Q[b + lane], P[b + lane]);
  float h1 = dech(Q[b + 64 + lane], P[b + 64 + lane]);
  float v = fmaf(h0, Wfc[lane], h1 * Wfc[64 + lane]);
#pragma unroll
  for (int off = 32; off > 0; off >>= 1) v += __shfl_down(v, off);
  if (lane == 0) out[node] = v + bfc[0];
}

extern "C" void kernel_launch(void* const* d_in, const int* in_sizes, int n_in,
                              void* d_out, int out_size, void* d_ws, size_t ws_size,
                              hipStream_t stream) {
  const float* x   = (const float*)d_in[0];
  const int*   ei  = (const int*)d_in[1];
  const float* Wm  = (const float*)d_in[2];
  const float* bm  = (const float*)d_in[3];
  const float* Wc  = (const float*)d_in[4];
  const float* bc  = (const float*)d_in[5];
  const float* Wg1 = (const float*)d_in[6];
  const float* bg1 = (const float*)d_in[7];
  const float* Wg2 = (const float*)d_in[8];
  const float* bg2 = (const float*)d_in[9];
  const float* Wg3 = (const float*)d_in[10];
  const float* bg3 = (const float*)d_in[11];
  const float* e1g = (const float*)d_in[12];
  const float* e1b = (const float*)d_in[13];
  const float* e1m = (const float*)d_in[14];
  const float* e1v = (const float*)d_in[15];
  const float* e1W = (const float*)d_in[16];
  const float* e2g = (const float*)d_in[17];
  const float* e2b = (const float*)d_in[18];
  const float* e2m = (const float*)d_in[19];
  const float* e2v = (const float*)d_in[20];
  const float* e2W = (const float*)d_in[21];
  const float* e3g = (const float*)d_in[22];
  const float* e3b = (const float*)d_in[23];
  const float* e3m = (const float*)d_in[24];
  const float* e3v = (const float*)d_in[25];
  const float* e3W = (const float*)d_in[26];
  const float* Wfc = (const float*)d_in[27];
  const float* bfc = (const float*)d_in[28];

  const int* src = ei;
  const int* dst = ei + N_EDGES;

  // ---- workspace layout (floats), ~63 MB ----
  float* ws    = (float*)d_ws;
  float* dinv  = ws;                                   // N
  float* dinv2 = dinv + N_NODES;                       // N
  float* u1    = dinv2 + N_NODES;                      // N
  float* w1    = u1 + N_NODES;                         // N
  float* u2    = w1 + N_NODES;                         // N
  float* y0    = u2 + N_NODES;                         // N*64
  float* za    = y0 + (size_t)N_NODES * 64;            // N*64
  float* zb    = za + (size_t)N_NODES * 64;            // N*64
  float* PQ    = zb + (size_t)N_NODES * 64;            // N*256 (P | Q)
  float* G     = PQ + (size_t)N_NODES * 256;           // N*256 (G; H1@base, H2@+N*128)
  float* sc1   = G + (size_t)N_NODES * 256;            // 512
  float* sh1   = sc1 + 512;
  float* sc2   = sh1 + 512;                            // 256
  float* sh2   = sc2 + 256;
  float* sc3   = sh2 + 256;
  float* sh3   = sc3 + 256;
  unsigned short* bf1p = (unsigned short*)(sh3 + 256);  // frag images, 512 KB total
  unsigned short* bf1q = bf1p + 65536;
  unsigned short* bf2p = bf1q + 65536;
  unsigned short* bf2q = bf2p + 32768;
  unsigned short* bf3p = bf2q + 32768;
  unsigned short* bf3q = bf3p + 32768;
  float* W12   = (float*)(bf3q + 32768);               // 64*128
  float* v1    = W12 + 8192;                           // 128
  float* W123  = v1 + 128;                             // 64*256
  float* c1    = W123 + 16384;                         // 256
  float* c2    = c1 + 256;                             // 256
  int* cnt     = (int*)(c2 + 256);                     // N
  int* row_ptr = cnt + N_NODES;                        // N+1
  int* cursor  = row_ptr + N_NODES + 1;                // N
  int* bsum    = cursor + N_NODES;                     // 256
  int* ssrc    = bsum + 256;                           // E
  int* sdst    = ssrc + N_EDGES;                       // E

  float*    Pbuf = PQ;
  unsigned* Qbuf = (unsigned*)(PQ + (size_t)N_NODES * 128);

  // ---- CSR build (counting sort by dst) + dinv/dinv2 ----
  hipMemsetAsync(cnt, 0, N_NODES * sizeof(int), stream);
  hist_kernel<<<N_EDGES / 256, 256, 0, stream>>>(dst, cnt, N_EDGES);
  scan_p1<<<79, 256, 0, stream>>>(cnt, row_ptr, bsum, dinv, dinv2, N_NODES);
  scan_p2<<<1, 256, 0, stream>>>(bsum, 79);
  scan_p3<<<79, 256, 0, stream>>>(row_ptr, bsum, cursor, N_NODES, N_EDGES);
  scatter_edges_kernel<<<N_EDGES / 256, 256, 0, stream>>>(src, dst, cursor, ssrc, sdst,
                                                          N_EDGES);

  // ---- setup: W frags + BN fold + W12/v1 + zero Q (one launch) ----
  setup_kernel<<<3046, 256, 0, stream>>>(e1W, e2W, e3W, bf1p, bf1q, bf2p, bf2q, bf3p, bf3q,
                                         e1g, e1b, e1m, e1v, sc1, sh1, e2g, e2b, e2m, e2v,
                                         sc2, sh2, e3g, e3b, e3m, e3v, sc3, sh3,
                                         Wg1, Wg2, bg1, W12, v1, Qbuf);

  // ---- mid: W123/c1/c2 + uvec1 ; then uvec2 ----
  mid_kernel<<<145, 256, 0, stream>>>(W12, Wg3, v1, bg2, W123, c1, c2, row_ptr, ssrc, dinv,
                                      u1, w1, N_NODES);
  uvec2_kernel<<<79, 256, 0, stream>>>(row_ptr, ssrc, dinv, w1, u2, N_NODES);

  // ---- linear GCN: G = A~^3 X0 W123 + u2 (x) c1 + u1 (x) c2 + b3 ----
  proj_kernel<<<N_NODES / 16, 256, 0, stream>>>(x, Wm, bm, Wc, bc, dinv, y0);
  agg_kernel<4><<<N_NODES * 16 / 256, 256, 0, stream>>>(y0, row_ptr, ssrc, dinv2, za, N_NODES);
  agg_kernel<4><<<N_NODES * 16 / 256, 256, 0, stream>>>(za, row_ptr, ssrc, dinv2, zb, N_NODES);
  agg_kernel<4><<<N_NODES * 16 / 256, 256, 0, stream>>>(zb, row_ptr, ssrc, dinv, za, N_NODES);
  dim3 grid4(313, 4);
  gemm_rank1_kernel<<<grid4, 256, 0, stream>>>(za, W123, bg3, u1, u2, c1, c2, G, N_NODES);

  const int EDGE_BLOCKS = N_EDGES / 64;             // 5000
  const int NODE_BLOCKS = (N_NODES + 63) / 64;      // 313
  const int EC_BLOCKS   = EDGE_BLOCKS + NODE_BLOCKS;
  const int NB_ELEM     = N_NODES * 128 / 256;      // 10000

  float* H1 = G;                        // combine1 -> G base (G dead after EC1)
  float* H2 = G + (size_t)N_NODES * 128;

  // EdgeConv 1: G [N,256] -> P/Q ; combine -> H1 [N,128]  (Q pre-zeroed by setup)
  ec_mfma_kernel<256><<<EC_BLOCKS, 256, 0, stream>>>(
      G, ssrc, sdst, sc1 + 256, sh1 + 256, bf1q, sc1, sh1, bf1p, Qbuf, Pbuf, N_NODES,
      EDGE_BLOCKS);
  combine_kernel<<<NB_ELEM, 256, 0, stream>>>(Qbuf, Pbuf, H1, N_NODES * 128);

  // EdgeConv 2: H1 -> P/Q ; combine -> H2
  ec_mfma_kernel<128><<<EC_BLOCKS, 256, 0, stream>>>(
      H1, ssrc, sdst, sc2 + 128, sh2 + 128, bf2q, sc2, sh2, bf2p, Qbuf, Pbuf, N_NODES,
      EDGE_BLOCKS);
  combine_kernel<<<NB_ELEM, 256, 0, stream>>>(Qbuf, Pbuf, H2, N_NODES * 128);

  // EdgeConv 3: H2 -> P/Q ; FC consumes P/Q directly (combine fused into FC)
  ec_mfma_kernel<128><<<EC_BLOCKS, 256, 0, stream>>>(
      H2, ssrc, sdst, sc3 + 128, sh3 + 128, bf3q, sc3, sh3, bf3p, Qbuf, Pbuf, N_NODES,
      EDGE_BLOCKS);
  fc_kernel<<<N_NODES * 64 / 256, 256, 0, stream>>>(Qbuf, Pbuf, Wfc, bfc, (float*)d_out,
                                                    N_NODES);
}